// Round 12
// baseline (540.532 us; speedup 1.0000x reference)
//
#include <hip/hip_runtime.h>
#include <hip/hip_bf16.h>
#include <stdint.h>

#define N_PTS 500000
#define NVOX  65536
#define K1_TILES ((N_PTS + 127) / 128)   // 3907
#define K3_TILES ((N_PTS + 63) / 64)     // 7813  (M=64 per block, 1024 threads)

typedef __attribute__((ext_vector_type(8))) short bf16x8;   // 8 x bf16 (4 VGPRs)
typedef __attribute__((ext_vector_type(4))) float f32x4;    // MFMA accumulator

__device__ inline unsigned short f2bf(float f) {
    union { float f; unsigned int u; } v; v.f = f;
    unsigned int r = v.u + 0x7FFFu + ((v.u >> 16) & 1u);   // RNE
    return (unsigned short)(r >> 16);
}
__device__ inline float bf2f(unsigned short h) {
    return __uint_as_float((unsigned int)h << 16);
}

// 16-byte global->LDS DMA: LDS dest is wave-uniform base + lane*16 (HW adds
// the lane offset); global src is per-lane. Zero VGPR staging cost.
__device__ inline void gld16(const void* g, void* l) {
    __builtin_amdgcn_global_load_lds(
        (const __attribute__((address_space(1))) unsigned int*)g,
        (__attribute__((address_space(3))) unsigned int*)l, 16, 0, 0);
}

// --------- fused weight prep: all transposes into one contiguous region ----
#define WOFF_W1T   0
#define WOFF_W2T   2048
#define WOFF_WV1T  10240
#define WOFF_W3AT  26624
#define WOFF_W3BT  59392
#define WOFF_W4T   92160
#define WOFF_WV2T  157696
#define W_TOTAL    223232

__global__ void prep_all(const float* __restrict__ W1, const float* __restrict__ W2,
                         const float* __restrict__ Wv1, const float* __restrict__ W3,
                         const float* __restrict__ W4, const float* __restrict__ Wv2,
                         unsigned short* __restrict__ dst) {
    int i = blockIdx.x * 256 + threadIdx.x;
    if (i >= W_TOTAL) return;
    int o = i;
    if (o < 2048) {                       // W1T: [64][32], pad k
        int n = o >> 5, k = o & 31;
        dst[i] = (k < 6) ? f2bf(W1[k * 64 + n]) : (unsigned short)0;
    } else if ((o -= 2048) < 8192) {      // W2T: K=64 Nn=128
        int n = o >> 6, k = o & 63;
        dst[i] = f2bf(W2[k * 128 + n]);
    } else if ((o -= 8192) < 16384) {     // Wv1T: K=128 Nn=128
        int n = o >> 7, k = o & 127;
        dst[i] = f2bf(Wv1[k * 128 + n]);
    } else if ((o -= 16384) < 32768) {    // W3aT: K=128 Nn=256 k0=0
        int n = o >> 7, k = o & 127;
        dst[i] = f2bf(W3[k * 256 + n]);
    } else if ((o -= 32768) < 32768) {    // W3bT: K=128 Nn=256 k0=128
        int n = o >> 7, k = o & 127;
        dst[i] = f2bf(W3[(k + 128) * 256 + n]);
    } else if ((o -= 32768) < 65536) {    // W4T: K=256 Nn=256
        int n = o >> 8, k = o & 255;
        dst[i] = f2bf(W4[k * 256 + n]);
    } else {                              // Wv2T
        o -= 65536;
        int n = o >> 8, k = o & 255;
        dst[i] = f2bf(Wv2[k * 256 + n]);
    }
}

// ------------------------- counting sort by voxel --------------------------
__global__ void s_hist(const int* __restrict__ idx, unsigned int* __restrict__ counts) {
    int p = blockIdx.x * 256 + threadIdx.x;
    if (p < N_PTS) atomicAdd(&counts[idx[p]], 1u);
}

__global__ __launch_bounds__(1024) void s_scan(const unsigned int* __restrict__ counts,
                                               unsigned int* __restrict__ cursor) {
    __shared__ unsigned int sPart[1024];
    int t = threadIdx.x;
    unsigned int sum = 0;
    #pragma unroll 8
    for (int i = 0; i < 64; i++) sum += counts[t * 64 + i];
    sPart[t] = sum;
    __syncthreads();
    for (int d = 1; d < 1024; d <<= 1) {
        unsigned int add = (t >= d) ? sPart[t - d] : 0u;
        __syncthreads();
        sPart[t] += add;
        __syncthreads();
    }
    unsigned int run = (t == 0) ? 0u : sPart[t - 1];
    #pragma unroll 8
    for (int i = 0; i < 64; i++) {
        cursor[t * 64 + i] = run;
        run += counts[t * 64 + i];
    }
}

__global__ void s_scatter(const int* __restrict__ idx, unsigned int* __restrict__ cursor,
                          int* __restrict__ order, int* __restrict__ svox) {
    int p = blockIdx.x * 256 + threadIdx.x;
    if (p < N_PTS) {
        int v = idx[p];
        unsigned int pos = atomicAdd(&cursor[v], 1u);
        order[pos] = p;
        svox[pos] = v;
    }
}

// ---------------------------------------------------------------------------
// K1 v2 (operand-swapped epilogues): mfma(b,a) computes C^T whose fragment
// layout gives each thread 4 CONSECUTIVE COLUMNS of one row -> epilogue is
// one aligned uint2 LDS store instead of 4 scattered u16 stores.
// ---------------------------------------------------------------------------
__global__ __launch_bounds__(256, 4) void k1_points(
    const float* __restrict__ inp,
    const int* __restrict__ order, const int* __restrict__ svox,
    const unsigned short* __restrict__ W1T, const float* __restrict__ b1,
    const unsigned short* __restrict__ W2T, const float* __restrict__ b2,
    unsigned int* __restrict__ vox1acc,      // [V][128] fp32-as-uint (zeroed)
    unsigned short* __restrict__ feat2seq)   // [N][128] bf16 sorted (or null)
{
    __shared__ __align__(16) char sBuf[32 * 1024];
    __shared__ __align__(16) float sb1[64];
    __shared__ __align__(16) float sb2[128];
    __shared__ int   sVox[128];
    char* sIn = sBuf;                // [128][32] bf16, row 64B,  swz (m&3)<<4
    char* sF1 = sBuf + 8 * 1024;     // [128][64] bf16, row 128B, swz (m&7)<<4
    char* sF2 = sBuf;                // [128][128] bf16, row 256B, swz (m&7)<<4
    const f32x4 fzero = {0.f, 0.f, 0.f, 0.f};
    int tid = threadIdx.x;
    int pbase = blockIdx.x * 128;
    if (tid < 64)       sb1[tid] = b1[tid];
    else if (tid < 192) sb2[tid - 64] = b2[tid - 64];
    if (tid < 128) {
        int i = pbase + tid;
        int pt = -1, v = -1;
        if (i < N_PTS) { pt = order[i]; v = svox[i]; }
        sVox[tid] = v;
        uint4 g0 = {0u, 0u, 0u, 0u};
        if (pt >= 0) {
            const float* x = inp + (size_t)pt * 6;
            g0.x = (unsigned)f2bf(x[0]) | ((unsigned)f2bf(x[1]) << 16);
            g0.y = (unsigned)f2bf(x[2]) | ((unsigned)f2bf(x[3]) << 16);
            g0.z = (unsigned)f2bf(x[4]) | ((unsigned)f2bf(x[5]) << 16);
        }
        int swz = (tid & 3) << 4;
        char* row = sIn + tid * 64;
        uint4 z = {0u, 0u, 0u, 0u};
        *(uint4*)(row + (0  ^ swz)) = g0;
        *(uint4*)(row + (16 ^ swz)) = z;
        *(uint4*)(row + (32 ^ swz)) = z;
        *(uint4*)(row + (48 ^ swz)) = z;
    }
    __syncthreads();
    int wave = tid >> 6, lane = tid & 63, quad = lane >> 4, l16 = lane & 15;

    // GEMM1: [128][32]@[32][64]  (swapped)
    {
        f32x4 acc1[8];
        #pragma unroll
        for (int mt = 0; mt < 8; mt++) acc1[mt] = fzero;
        bf16x8 b = *(const bf16x8*)(W1T + (wave * 16 + l16) * 32 + quad * 8);
        #pragma unroll
        for (int mt = 0; mt < 8; mt++) {
            int m = mt * 16 + l16;
            bf16x8 a = *(const bf16x8*)(sIn + m * 64 + ((quad * 16) ^ ((m & 3) << 4)));
            acc1[mt] = __builtin_amdgcn_mfma_f32_16x16x32_bf16(b, a, acc1[mt], 0, 0, 0);
        }
        int nb = wave * 16 + quad * 4;
        float4 bi = *(const float4*)&sb1[nb];
        #pragma unroll
        for (int mt = 0; mt < 8; mt++) {
            int m = mt * 16 + l16;
            uint2 pk;
            pk.x = (unsigned)f2bf(fmaxf(acc1[mt][0] + bi.x, 0.f))
                 | ((unsigned)f2bf(fmaxf(acc1[mt][1] + bi.y, 0.f)) << 16);
            pk.y = (unsigned)f2bf(fmaxf(acc1[mt][2] + bi.z, 0.f))
                 | ((unsigned)f2bf(fmaxf(acc1[mt][3] + bi.w, 0.f)) << 16);
            *(uint2*)(sF1 + m * 128 + ((2 * nb) ^ ((m & 7) << 4))) = pk;
        }
    }
    __syncthreads();
    // GEMM2: [128][64]@[64][128]  (swapped)
    f32x4 acc2[2][8];
    #pragma unroll
    for (int j = 0; j < 2; j++)
        #pragma unroll
        for (int mt = 0; mt < 8; mt++) acc2[j][mt] = fzero;
    #pragma unroll
    for (int kt = 0; kt < 2; kt++) {
        bf16x8 b0 = *(const bf16x8*)(W2T + ((wave * 2 + 0) * 16 + l16) * 64 + kt * 32 + quad * 8);
        bf16x8 b1 = *(const bf16x8*)(W2T + ((wave * 2 + 1) * 16 + l16) * 64 + kt * 32 + quad * 8);
        #pragma unroll
        for (int mt = 0; mt < 8; mt++) {
            int m = mt * 16 + l16;
            bf16x8 a = *(const bf16x8*)(sF1 + m * 128 + ((kt * 64 + quad * 16) ^ ((m & 7) << 4)));
            acc2[0][mt] = __builtin_amdgcn_mfma_f32_16x16x32_bf16(b0, a, acc2[0][mt], 0, 0, 0);
            acc2[1][mt] = __builtin_amdgcn_mfma_f32_16x16x32_bf16(b1, a, acc2[1][mt], 0, 0, 0);
        }
    }
    __syncthreads();   // all sIn/sF1 reads done before sF2 overwrite
    #pragma unroll
    for (int j = 0; j < 2; j++) {
        int nb = (wave * 2 + j) * 16 + quad * 4;
        float4 bi = *(const float4*)&sb2[nb];
        #pragma unroll
        for (int mt = 0; mt < 8; mt++) {
            int m = mt * 16 + l16;
            uint2 pk;
            pk.x = (unsigned)f2bf(fmaxf(acc2[j][mt][0] + bi.x, 0.f))
                 | ((unsigned)f2bf(fmaxf(acc2[j][mt][1] + bi.y, 0.f)) << 16);
            pk.y = (unsigned)f2bf(fmaxf(acc2[j][mt][2] + bi.z, 0.f))
                 | ((unsigned)f2bf(fmaxf(acc2[j][mt][3] + bi.w, 0.f)) << 16);
            *(uint2*)(sF2 + m * 256 + ((2 * nb) ^ ((m & 7) << 4))) = pk;
        }
    }
    __syncthreads();
    // spill feat2 (sorted order) to global for k3_lite — coalesced uint4
    if (feat2seq) {
        #pragma unroll
        for (int it = 0; it < 8; it++) {
            int i = tid + 256 * it;
            int m = i >> 4, q = i & 15;
            if (pbase + m < N_PTS) {
                uint4 val = *(const uint4*)(sF2 + m * 256 + ((q * 16) ^ ((m & 7) << 4)));
                *(uint4*)(feat2seq + (size_t)(pbase + m) * 128 + q * 8) = val;
            }
        }
    }
    // segmented max walk; interior segments -> plain store
    {
        int c = tid & 127, r0 = (tid >> 7) * 64;
        int cur = -1; float vmax = 0.f; int segStart = r0;
        for (int r = r0; r < r0 + 64; r++) {
            int v = sVox[r];
            float f = bf2f(*(const unsigned short*)(sF2 + r * 256 + ((2 * c) ^ ((r & 7) << 4))));
            if (v != cur) {
                if (cur >= 0) {
                    if (segStart > r0)
                        vox1acc[(size_t)cur * 128 + c] = __float_as_uint(vmax);
                    else
                        atomicMax(vox1acc + (size_t)cur * 128 + c, __float_as_uint(vmax));
                }
                cur = v; vmax = f; segStart = r;
            } else vmax = fmaxf(vmax, f);
        }
        if (cur >= 0)
            atomicMax(vox1acc + (size_t)cur * 128 + c, __float_as_uint(vmax));
    }
}

// ---------------------------------------------------------------------------
// kvox2 v2 (operand-swapped epilogues): GEMM A LDS epilogue -> one uint2
// store; GEMM B global voxB write -> one aligned uint2 store per (j,mt)
// (4x fewer stores, 8B coalesced vs 4 scattered u16). Readers unchanged.
// ---------------------------------------------------------------------------
__global__ __launch_bounds__(256, 4) void kvox2(
    const float* __restrict__ in, const unsigned short* __restrict__ Wv1T,
    const float* __restrict__ bv1, const unsigned short* __restrict__ W3aT,
    unsigned short* __restrict__ voxB)     // [V][256] bf16, aliases `in`
{
    __shared__ __align__(16) char sA[64 * 256];   // [64][128] bf16 input
    __shared__ __align__(16) char sB[64 * 256];   // [64][128] bf16 voxA
    __shared__ __align__(16) float sb[128];
    const f32x4 fzero = {0.f, 0.f, 0.f, 0.f};
    int tid = threadIdx.x;
    int vb = blockIdx.x * 64;
    if (tid < 128) sb[tid] = bv1[tid];
    #pragma unroll
    for (int it = 0; it < 8; it++) {
        int i = tid + 256 * it;
        int m = i >> 5, kq = i & 31;
        float4 f = ((const float4*)(in + (size_t)(vb + m) * 128))[kq];
        uint2 p;
        p.x = (unsigned)f2bf(f.x) | ((unsigned)f2bf(f.y) << 16);
        p.y = (unsigned)f2bf(f.z) | ((unsigned)f2bf(f.w) << 16);
        *(uint2*)(sA + m * 256 + ((8 * kq) ^ ((m & 7) << 4))) = p;
    }
    __syncthreads();
    int wave = tid >> 6, lane = tid & 63, quad = lane >> 4, l16 = lane & 15;
    // GEMM A: voxA = relu([64][128]@[128][128] + bv1)  (swapped)
    {
        f32x4 acc[2][4];
        #pragma unroll
        for (int j = 0; j < 2; j++)
            #pragma unroll
            for (int mt = 0; mt < 4; mt++) acc[j][mt] = fzero;
        #pragma unroll
        for (int kt = 0; kt < 4; kt++) {
            bf16x8 a[4];
            #pragma unroll
            for (int mt = 0; mt < 4; mt++) {
                int m = mt * 16 + l16;
                a[mt] = *(const bf16x8*)(sA + m * 256 + ((kt * 64 + quad * 16) ^ ((m & 7) << 4)));
            }
            #pragma unroll
            for (int j = 0; j < 2; j++) {
                int n = (wave * 2 + j) * 16 + l16;
                bf16x8 b = *(const bf16x8*)(Wv1T + n * 128 + kt * 32 + quad * 8);
                #pragma unroll
                for (int mt = 0; mt < 4; mt++)
                    acc[j][mt] = __builtin_amdgcn_mfma_f32_16x16x32_bf16(b, a[mt], acc[j][mt], 0, 0, 0);
            }
        }
        #pragma unroll
        for (int j = 0; j < 2; j++) {
            int nb = (wave * 2 + j) * 16 + quad * 4;
            float4 bi = *(const float4*)&sb[nb];
            #pragma unroll
            for (int mt = 0; mt < 4; mt++) {
                int m = mt * 16 + l16;
                uint2 pk;
                pk.x = (unsigned)f2bf(fmaxf(acc[j][mt][0] + bi.x, 0.f))
                     | ((unsigned)f2bf(fmaxf(acc[j][mt][1] + bi.y, 0.f)) << 16);
                pk.y = (unsigned)f2bf(fmaxf(acc[j][mt][2] + bi.z, 0.f))
                     | ((unsigned)f2bf(fmaxf(acc[j][mt][3] + bi.w, 0.f)) << 16);
                *(uint2*)(sB + m * 256 + ((2 * nb) ^ ((m & 7) << 4))) = pk;
            }
        }
    }
    __syncthreads();
    // GEMM B: voxB = voxA@[128][256]; no bias/relu  (swapped; uint2 global)
    {
        f32x4 acc[4][4];
        #pragma unroll
        for (int j = 0; j < 4; j++)
            #pragma unroll
            for (int mt = 0; mt < 4; mt++) acc[j][mt] = fzero;
        #pragma unroll
        for (int kt = 0; kt < 4; kt++) {
            bf16x8 a[4];
            #pragma unroll
            for (int mt = 0; mt < 4; mt++) {
                int m = mt * 16 + l16;
                a[mt] = *(const bf16x8*)(sB + m * 256 + ((kt * 64 + quad * 16) ^ ((m & 7) << 4)));
            }
            #pragma unroll
            for (int j = 0; j < 4; j++) {
                int n = (wave * 4 + j) * 16 + l16;
                bf16x8 b = *(const bf16x8*)(W3aT + n * 128 + kt * 32 + quad * 8);
                #pragma unroll
                for (int mt = 0; mt < 4; mt++)
                    acc[j][mt] = __builtin_amdgcn_mfma_f32_16x16x32_bf16(b, a[mt], acc[j][mt], 0, 0, 0);
            }
        }
        #pragma unroll
        for (int j = 0; j < 4; j++) {
            int nb = (wave * 4 + j) * 16 + quad * 4;
            #pragma unroll
            for (int mt = 0; mt < 4; mt++) {
                int m = mt * 16 + l16;
                uint2 pk;
                pk.x = (unsigned)f2bf(acc[j][mt][0]) | ((unsigned)f2bf(acc[j][mt][1]) << 16);
                pk.y = (unsigned)f2bf(acc[j][mt][2]) | ((unsigned)f2bf(acc[j][mt][3]) << 16);
                *(uint2*)(voxB + (size_t)(vb + m) * 256 + nb) = pk;
            }
        }
    }
}

// ---------------------------------------------------------------------------
// K3 LITE v12 (R11 winner, unchanged): swapped GEMM3'/GEMM4 epilogues.
// ---------------------------------------------------------------------------
__global__ __launch_bounds__(1024, 8) void k3_lite(
    const int* __restrict__ svox,
    const unsigned short* __restrict__ feat2seq, // [N][128] bf16 sorted
    const unsigned short* __restrict__ voxB,     // [V][256] bf16
    const unsigned short* __restrict__ W3bT, const float* __restrict__ b3,
    const unsigned short* __restrict__ W4T, const float* __restrict__ b4,
    unsigned int* __restrict__ vox2acc)          // [V][256] fp32-as-uint (zeroed)
{
    __shared__ __align__(16) char sBuf[32 * 1024];
    __shared__ __align__(16) float sb3[256];
    __shared__ __align__(16) float sb4[256];
    __shared__ int   sVox[64];
    char* sP  = sBuf;               // [64][256] bf16, row 512B: gather/feat4/feat5
    char* sF2 = sBuf + 16 * 1024;   // [64][128] bf16, row 256B: feat2 (dies post-GEMM3')
    const f32x4 fzero = {0.f, 0.f, 0.f, 0.f};
    int tid = threadIdx.x;
    int pbase = blockIdx.x * 64;
    int wave = tid >> 6, lane = tid & 63, quad = lane >> 4, l16 = lane & 15;
    if (tid < 256)      sb3[tid] = b3[tid];
    else if (tid < 512) sb4[tid - 256] = b4[tid - 256];
    if (tid < 64) {
        int i = pbase + tid;
        sVox[tid] = (i < N_PTS) ? svox[i] : -1;
    }
    // voxB rows 32-63 -> held register (1 uint4/thread, T14 issue-early).
    uint4 hv = {0u, 0u, 0u, 0u};
    int hm = 32 + (tid >> 5);          // row 32..63
    int hc = tid & 31;                 // 16B unit 0..31
    {
        int p = pbase + hm;
        if (p < N_PTS)
            hv = ((const uint4*)(voxB + (size_t)svox[p] * 256))[hc];
    }
    // voxB rows 0-31 -> sP low 16K via DMA; 16 chunks of 1KB, chunk q = wave.
    {
        int q = wave;
        int m = 2 * q + (lane >> 5);
        int u = lane & 31;
        int p = pbase + m; if (p >= N_PTS) p = N_PTS - 1;   // clamp: garbage rows dead via sVox
        gld16(voxB + (size_t)svox[p] * 256 + (size_t)(u ^ (m & 7)) * 8,
              sP + q * 1024);
    }
    // feat2 -> sF2 via DMA; chunk q = wave = 4 rows of 256B.
    {
        int q = wave;
        int m = 4 * q + (lane >> 4);
        int u = lane & 15;
        int p = pbase + m; if (p >= N_PTS) p = N_PTS - 1;
        gld16(feat2seq + (size_t)p * 128 + (size_t)(u ^ (m & 7)) * 8,
              sF2 + q * 1024);
    }
    __syncthreads();   // drains DMA (vmcnt) + sVox/sb visible

    int n = wave * 16 + l16;    // b-frag column index (per-lane)
    int nb = wave * 16 + quad * 4;   // this thread's 4 output columns (swapped C^T)

    // GEMM3': [64][128] @ [128][256]; swapped mfma(b,a)
    f32x4 acc[4];
    #pragma unroll
    for (int mt = 0; mt < 4; mt++) acc[mt] = fzero;
    #pragma unroll
    for (int kt = 0; kt < 4; kt++) {
        bf16x8 b = *(const bf16x8*)(W3bT + n * 128 + kt * 32 + quad * 8);
        #pragma unroll
        for (int mt = 0; mt < 4; mt++) {
            int m = mt * 16 + l16;
            bf16x8 a = *(const bf16x8*)(sF2 + m * 256 + ((kt * 64 + quad * 16) ^ ((m & 7) << 4)));
            acc[mt] = __builtin_amdgcn_mfma_f32_16x16x32_bf16(b, a, acc[mt], 0, 0, 0);
        }
    }
    __syncthreads();   // all sF2 reads done — its space becomes sP rows 32-63
    // write held voxB rows 32-63 into sP (dest-swizzled LDS write)
    *(uint4*)(sP + hm * 512 + ((hc * 16) ^ ((hm & 7) << 4))) = hv;
    __syncthreads();   // voxB rows 32-63 visible
    // feat4 = relu(acc + b3 + voxpart) -> sP in-place; one uint2 RMW per mt
    {
        float4 bi = *(const float4*)&sb3[nb];
        #pragma unroll
        for (int mt = 0; mt < 4; mt++) {
            int m = mt * 16 + l16;
            char* p = sP + m * 512 + ((2 * nb) ^ ((m & 7) << 4));
            uint2 vv = *(const uint2*)p;
            float v0 = fmaxf(acc[mt][0] + bi.x + bf2f((unsigned short)vv.x), 0.f);
            float v1 = fmaxf(acc[mt][1] + bi.y + bf2f((unsigned short)(vv.x >> 16)), 0.f);
            float v2 = fmaxf(acc[mt][2] + bi.z + bf2f((unsigned short)vv.y), 0.f);
            float v3 = fmaxf(acc[mt][3] + bi.w + bf2f((unsigned short)(vv.y >> 16)), 0.f);
            uint2 pk;
            pk.x = (unsigned)f2bf(v0) | ((unsigned)f2bf(v1) << 16);
            pk.y = (unsigned)f2bf(v2) | ((unsigned)f2bf(v3) << 16);
            *(uint2*)p = pk;
        }
    }
    __syncthreads();
    #pragma unroll
    for (int mt = 0; mt < 4; mt++) acc[mt] = fzero;
    // GEMM4: [64][256] @ [256][256]; swapped mfma(b,a)
    #pragma unroll 4
    for (int kt = 0; kt < 8; kt++) {
        bf16x8 b = *(const bf16x8*)(W4T + n * 256 + kt * 32 + quad * 8);
        #pragma unroll
        for (int mt = 0; mt < 4; mt++) {
            int m = mt * 16 + l16;
            bf16x8 a = *(const bf16x8*)(sP + m * 512 + ((kt * 64 + quad * 16) ^ ((m & 7) << 4)));
            acc[mt] = __builtin_amdgcn_mfma_f32_16x16x32_bf16(b, a, acc[mt], 0, 0, 0);
        }
    }
    __syncthreads();   // all feat4 reads done before feat5 overwrite
    // feat5 = relu(acc + b4) -> sP; one uint2 store per mt
    {
        float4 bi = *(const float4*)&sb4[nb];
        #pragma unroll
        for (int mt = 0; mt < 4; mt++) {
            int m = mt * 16 + l16;
            uint2 pk;
            pk.x = (unsigned)f2bf(fmaxf(acc[mt][0] + bi.x, 0.f))
                 | ((unsigned)f2bf(fmaxf(acc[mt][1] + bi.y, 0.f)) << 16);
            pk.y = (unsigned)f2bf(fmaxf(acc[mt][2] + bi.z, 0.f))
                 | ((unsigned)f2bf(fmaxf(acc[mt][3] + bi.w, 0.f)) << 16);
            *(uint2*)(sP + m * 512 + ((2 * nb) ^ ((m & 7) << 4))) = pk;
        }
    }
    __syncthreads();
    // segmented max: c = tid&255 (256 cols), four 16-row walkers per column;
    // interior segments -> plain store, boundary -> atomicMax (k1's pattern)
    {
        int c = tid & 255, r0 = (tid >> 8) * 16;
        int cur = -1; float vmax = 0.f; int segStart = r0;
        for (int r = r0; r < r0 + 16; r++) {
            int v = sVox[r];
            float f = bf2f(*(const unsigned short*)(sP + r * 512 + ((2 * c) ^ ((r & 7) << 4))));
            if (v != cur) {
                if (cur >= 0) {
                    if (segStart > r0)
                        vox2acc[(size_t)cur * 256 + c] = __float_as_uint(vmax);
                    else
                        atomicMax(vox2acc + (size_t)cur * 256 + c, __float_as_uint(vmax));
                }
                cur = v; vmax = f; segStart = r;
            } else vmax = fmaxf(vmax, f);
        }
        if (cur >= 0)
            atomicMax(vox2acc + (size_t)cur * 256 + c, __float_as_uint(vmax));
    }
}

// ---------------------------------------------------------------------------
// K3 v8 (FALLBACK, used only when workspace can't hold feat2seq):
// recomputes feat1/feat2 per tile. Unchanged from previous best.
// ---------------------------------------------------------------------------
__global__ __launch_bounds__(256, 3) void k3_heavy(
    const float* __restrict__ inp,
    const int* __restrict__ order, const int* __restrict__ svox,
    const unsigned short* __restrict__ W1T, const float* __restrict__ b1,
    const unsigned short* __restrict__ W2T, const float* __restrict__ b2,
    const unsigned short* __restrict__ voxB,     // [V][256] bf16
    const unsigned short* __restrict__ W3bT, const float* __restrict__ b3,
    const unsigned short* __restrict__ W4T, const float* __restrict__ b4,
    unsigned int* __restrict__ vox2acc)          // [V][256] fp32-as-uint (zeroed)
{
    __shared__ __align__(16) char sBuf[32 * 1024];
    __shared__ float sb1[64];
    __shared__ float sb2[128];
    __shared__ float sb3[256];
    __shared__ float sb4[256];
    __shared__ int   sVox[64];
    char* sF2 = sBuf;                 // [64][128] bf16, row 256B  (dies after GEMM3')
    char* sF1 = sBuf + 16 * 1024;     // [64][64]  bf16, row 128B  (phase 1-2)
    char* sIn = sBuf + 24 * 1024;     // [64][32]  bf16, row 64B   (phase 0-1)
    char* sP  = sBuf;                 // [64][256] bf16, row 512B  (gather onward)
    const f32x4 fzero = {0.f, 0.f, 0.f, 0.f};
    int tid = threadIdx.x;
    int pbase = blockIdx.x * 64;
    sb3[tid] = b3[tid];
    sb4[tid] = b4[tid];
    if (tid < 64)  sb1[tid] = b1[tid];
    if (tid < 128) sb2[tid] = b2[tid];
    if (tid < 64) {
        int i = pbase + tid;
        int pt = -1, v = -1;
        if (i < N_PTS) { pt = order[i]; v = svox[i]; }
        sVox[tid] = v;
        uint4 g0 = {0u, 0u, 0u, 0u};
        if (pt >= 0) {
            const float* x = inp + (size_t)pt * 6;
            g0.x = (unsigned)f2bf(x[0]) | ((unsigned)f2bf(x[1]) << 16);
            g0.y = (unsigned)f2bf(x[2]) | ((unsigned)f2bf(x[3]) << 16);
            g0.z = (unsigned)f2bf(x[4]) | ((unsigned)f2bf(x[5]) << 16);
        }
        int swz = (tid & 3) << 4;
        char* row = sIn + tid * 64;
        uint4 z = {0u, 0u, 0u, 0u};
        *(uint4*)(row + (0  ^ swz)) = g0;
        *(uint4*)(row + (16 ^ swz)) = z;
        *(uint4*)(row + (32 ^ swz)) = z;
        *(uint4*)(row + (48 ^ swz)) = z;
    }
    __syncthreads();
    int wave = tid >> 6, lane = tid & 63, quad = lane >> 4, l16 = lane & 15;

    // GEMM1: feat1 = relu([64][32]@[32][64] + b1); wave owns n-tile `wave`
    {
        f32x4 acc1[4];
        #pragma unroll
        for (int mt = 0; mt < 4; mt++) acc1[mt] = fzero;
        int n = wave * 16 + l16;
        bf16x8 b = *(const bf16x8*)(W1T + n * 32 + quad * 8);
        #pragma unroll
        for (int mt = 0; mt < 4; mt++) {
            int m = mt * 16 + l16;
            bf16x8 a = *(const bf16x8*)(sIn + m * 64 + ((quad * 16) ^ ((m & 3) << 4)));
            acc1[mt] = __builtin_amdgcn_mfma_f32_16x16x32_bf16(a, b, acc1[mt], 0, 0, 0);
        }
        float bias = sb1[n];
        #pragma unroll
        for (int mt = 0; mt < 4; mt++)
            #pragma unroll
            for (int r = 0; r < 4; r++) {
                int m = mt * 16 + quad * 4 + r;
                float v = fmaxf(acc1[mt][r] + bias, 0.f);
                *(unsigned short*)(sF1 + m * 128 + ((2 * n) ^ ((m & 7) << 4))) = f2bf(v);
            }
    }
    __syncthreads();
    // GEMM2: feat2 = relu([64][64]@[64][128] + b2); wave owns n-tiles 2w,2w+1
    {
        f32x4 acc2[2][4];
        #pragma unroll
        for (int j = 0; j < 2; j++)
            #pragma unroll
            for (int mt = 0; mt < 4; mt++) acc2[j][mt] = fzero;
        #pragma unroll
        for (int kt = 0; kt < 2; kt++) {
            bf16x8 b0 = *(const bf16x8*)(W2T + ((wave * 2 + 0) * 16 + l16) * 64 + kt * 32 + quad * 8);
            bf16x8 b1 = *(const bf16x8*)(W2T + ((wave * 2 + 1) * 16 + l16) * 64 + kt * 32 + quad * 8);
            #pragma unroll
            for (int mt = 0; mt < 4; mt++) {
                int m = mt * 16 + l16;
                bf16x8 a = *(const bf16x8*)(sF1 + m * 128 + ((kt * 64 + quad * 16) ^ ((m & 7) << 4)));
                acc2[0][mt] = __builtin_amdgcn_mfma_f32_16x16x32_bf16(a, b0, acc2[0][mt], 0, 0, 0);
                acc2[1][mt] = __builtin_amdgcn_mfma_f32_16x16x32_bf16(a, b1, acc2[1][mt], 0, 0, 0);
            }
        }
        #pragma unroll
        for (int j = 0; j < 2; j++) {
            int n = (wave * 2 + j) * 16 + l16;
            float bias = sb2[n];
            #pragma unroll
            for (int mt = 0; mt < 4; mt++)
                #pragma unroll
                for (int r = 0; r < 4; r++) {
                    int m = mt * 16 + quad * 4 + r;
                    float v = fmaxf(acc2[j][mt][r] + bias, 0.f);
                    *(unsigned short*)(sF2 + m * 256 + ((2 * n) ^ ((m & 7) << 4))) = f2bf(v);
                }
        }
    }
    __syncthreads();   // sF1/sIn dead; sF2 complete

    // GEMM3': [64][128] @ [128][256]; wave owns 4 n-tiles x 4 m-tiles
    f32x4 acc[4][4];
    #pragma unroll
    for (int j = 0; j < 4; j++)
        #pragma unroll
        for (int mt = 0; mt < 4; mt++) acc[j][mt] = fzero;
    #pragma unroll 1
    for (int kt = 0; kt < 4; kt++) {
        bf16x8 a[4];
        #pragma unroll
        for (int mt = 0; mt < 4; mt++) {
            int m = mt * 16 + l16;
            a[mt] = *(const bf16x8*)(sF2 + m * 256 + ((kt * 64 + quad * 16) ^ ((m & 7) << 4)));
        }
        #pragma unroll
        for (int j = 0; j < 4; j++) {
            int n = (wave * 4 + j) * 16 + l16;
            bf16x8 b = *(const bf16x8*)(W3bT + n * 128 + kt * 32 + quad * 8);
            #pragma unroll
            for (int mt = 0; mt < 4; mt++)
                acc[j][mt] = __builtin_amdgcn_mfma_f32_16x16x32_bf16(a[mt], b, acc[j][mt], 0, 0, 0);
        }
    }
    __syncthreads();   // sF2 reads complete — arena becomes sP
    // gather voxB rows -> sP [64][256] (sorted -> dedup, L2 hits)
    #pragma unroll
    for (int it = 0; it < 8; it++) {
        int i = tid + 256 * it;
        int m = i >> 5, c = i & 31;
        int vv = sVox[m];
        uint4 val = {0u, 0u, 0u, 0u};
        if (vv >= 0)
            val = ((const uint4*)(voxB + (size_t)vv * 256))[c];
        *(uint4*)(sP + m * 512 + ((c * 16) ^ ((m & 7) << 4))) = val;
    }
    __syncthreads();
    // feat4 = relu(acc + b3 + voxpart) -> sP in-place
    #pragma unroll
    for (int j = 0; j < 4; j++) {
        int n = (wave * 4 + j) * 16 + l16;
        float bias = sb3[n];
        #pragma unroll
        for (int mt = 0; mt < 4; mt++)
            #pragma unroll
            for (int r = 0; r < 4; r++) {
                int m = mt * 16 + quad * 4 + r;
                char* p = sP + m * 512 + ((2 * n) ^ ((m & 7) << 4));
                float vox = bf2f(*(const unsigned short*)p);
                float v = fmaxf(acc[j][mt][r] + bias + vox, 0.f);
                *(unsigned short*)p = f2bf(v);
            }
    }
    __syncthreads();
    #pragma unroll
    for (int j = 0; j < 4; j++)
        #pragma unroll
        for (int mt = 0; mt < 4; mt++) acc[j][mt] = fzero;
    // GEMM4: [64][256] @ [256][256]
    #pragma unroll 1
    for (int kt = 0; kt < 8; kt++) {
        bf16x8 a[4];
        #pragma unroll
        for (int mt = 0; mt < 4; mt++) {
            int m = mt * 16 + l16;
            a[mt] = *(const bf16x8*)(sP + m * 512 + ((kt * 64 + quad * 16) ^ ((m & 7) << 4)));
        }
        #pragma unroll
        for (int j = 0; j < 4; j++) {
            int n = (wave * 4 + j) * 16 + l16;
            bf16x8 b = *(const bf16x8*)(W4T + n * 256 + kt * 32 + quad * 8);
            #pragma unroll
            for (int mt = 0; mt < 4; mt++)
                acc[j][mt] = __builtin_amdgcn_mfma_f32_16x16x32_bf16(a[mt], b, acc[j][mt], 0, 0, 0);
        }
    }
    __syncthreads();   // all feat4 reads done before feat5 overwrite
    // feat5 = relu(acc + b4) -> sP
    #pragma unroll
    for (int j = 0; j < 4; j++) {
        int n = (wave * 4 + j) * 16 + l16;
        float bias = sb4[n];
        #pragma unroll
        for (int mt = 0; mt < 4; mt++)
            #pragma unroll
            for (int r = 0; r < 4; r++) {
                int m = mt * 16 + quad * 4 + r;
                float v = fmaxf(acc[j][mt][r] + bias, 0.f);
                *(unsigned short*)(sP + m * 512 + ((2 * n) ^ ((m & 7) << 4))) = f2bf(v);
            }
    }
    __syncthreads();
    // segmented max: c = tid (256 cols), 64 rows; interior -> plain store
    {
        int c = tid;
        int cur = -1; float vmax = 0.f; int segStart = 0;
        for (int r = 0; r < 64; r++) {
            int v = sVox[r];
            float f = bf2f(*(const unsigned short*)(sP + r * 512 + ((2 * c) ^ ((r & 7) << 4))));
            if (v != cur) {
                if (cur >= 0) {
                    if (segStart > 0)
                        vox2acc[(size_t)cur * 256 + c] = __float_as_uint(vmax);
                    else
                        atomicMax(vox2acc + (size_t)cur * 256 + c, __float_as_uint(vmax));
                }
                cur = v; vmax = f; segStart = r;
            } else vmax = fmaxf(vmax, f);
        }
        if (cur >= 0)
            atomicMax(vox2acc + (size_t)cur * 256 + c, __float_as_uint(vmax));
    }
}

// ---------------------------------------------------------------------------
// kvox_final v2 (swapped): out = relu(in @ Wv2 + bv2); epilogue is one
// aligned float4 global store per (j,mt) — 4x fewer, fully coalesced.
// Safe for in == out.
// ---------------------------------------------------------------------------
__global__ __launch_bounds__(256, 4) void kvox_final(
    const float* __restrict__ in, const unsigned short* __restrict__ WT,
    const float* __restrict__ bias, float* __restrict__ outp)
{
    __shared__ __align__(16) char sA[64 * 512];
    __shared__ __align__(16) float sb[256];
    const f32x4 fzero = {0.f, 0.f, 0.f, 0.f};
    int tid = threadIdx.x;
    int vb = blockIdx.x * 64;
    sb[tid] = bias[tid];
    #pragma unroll
    for (int it = 0; it < 16; it++) {
        int i = tid + 256 * it;
        int m = i >> 6, kq = i & 63;
        float4 f = ((const float4*)(in + (size_t)(vb + m) * 256))[kq];
        uint2 p;
        p.x = (unsigned)f2bf(f.x) | ((unsigned)f2bf(f.y) << 16);
        p.y = (unsigned)f2bf(f.z) | ((unsigned)f2bf(f.w) << 16);
        *(uint2*)(sA + m * 512 + ((8 * kq) ^ ((m & 7) << 4))) = p;
    }
    __syncthreads();
    int wave = tid >> 6, lane = tid & 63, quad = lane >> 4, l16 = lane & 15;
    f32x4 acc[4][4];
    #pragma unroll
    for (int j = 0; j < 4; j++)
        #pragma unroll
        for (int mt = 0; mt < 4; mt++) acc[j][mt] = fzero;
    #pragma unroll 1
    for (int kt = 0; kt < 8; kt++) {
        bf16x8 a[4];
        #pragma unroll
        for (int mt = 0; mt < 4; mt++) {
            int m = mt * 16 + l16;
            a[mt] = *(const bf16x8*)(sA + m * 512 + ((kt * 64 + quad * 16) ^ ((m & 7) << 4)));
        }
        #pragma unroll
        for (int j = 0; j < 4; j++) {
            int n = (wave * 4 + j) * 16 + l16;
            bf16x8 b = *(const bf16x8*)(WT + n * 256 + kt * 32 + quad * 8);
            #pragma unroll
            for (int mt = 0; mt < 4; mt++)
                acc[j][mt] = __builtin_amdgcn_mfma_f32_16x16x32_bf16(b, a[mt], acc[j][mt], 0, 0, 0);
        }
    }
    #pragma unroll
    for (int j = 0; j < 4; j++) {
        int nb = (wave * 4 + j) * 16 + quad * 4;
        float4 bi = *(const float4*)&sb[nb];
        #pragma unroll
        for (int mt = 0; mt < 4; mt++) {
            int m = mt * 16 + l16;
            float4 o;
            o.x = fmaxf(acc[j][mt][0] + bi.x, 0.f);
            o.y = fmaxf(acc[j][mt][1] + bi.y, 0.f);
            o.z = fmaxf(acc[j][mt][2] + bi.z, 0.f);
            o.w = fmaxf(acc[j][mt][3] + bi.w, 0.f);
            *(float4*)(outp + (size_t)(vb + m) * 256 + nb) = o;
        }
    }
}

extern "C" void kernel_launch(void* const* d_in, const int* in_sizes, int n_in,
                              void* d_out, int out_size, void* d_ws, size_t ws_size,
                              hipStream_t stream) {
    const float* inp  = (const float*)d_in[0];
    const int*   idx  = (const int*)d_in[1];
    const float* W1   = (const float*)d_in[2];
    const float* b1   = (const float*)d_in[3];
    const float* W2   = (const float*)d_in[4];
    const float* b2   = (const float*)d_in[5];
    const float* Wv1  = (const float*)d_in[6];
    const float* bv1  = (const float*)d_in[7];
    const float* W3   = (const float*)d_in[8];
    const float* b3   = (const float*)d_in[9];
    const float* W4   = (const float*)d_in[10];
    const float* b4   = (const float*)d_in[11];
    const float* Wv2  = (const float*)d_in[12];
    const float* bv2  = (const float*)d_in[13];

    // workspace layout — base ~38 MB; +122 MB feat2seq when it fits
    char* ws = (char*)d_ws;
    size_t off = 0;
    unsigned int*   vox1acc = (unsigned int*)(ws + off);   off += (size_t)NVOX * 128 * 4;  // 32 MB
    unsigned int*   counts  = (unsigned int*)(ws + off);   off += (size_t)NVOX * 4;
    unsigned int*   cursor  = (unsigned int*)(ws + off);   off += (size_t)NVOX * 4;
    int*            order   = (int*)(ws + off);            off += (size_t)N_PTS * 4;
    int*            svox    = (int*)(ws + off);            off += (size_t)N_PTS * 4;
    unsigned short* wsW     = (unsigned short*)(ws + off); off += (size_t)W_TOTAL * 2;

    unsigned short* feat2seq = nullptr;                    // [N][128] bf16 sorted
    if (ws_size >= off + (size_t)N_PTS * 128 * 2)
        feat2seq = (unsigned short*)(ws + off);

    const unsigned short* W1T  = wsW + WOFF_W1T;
    const unsigned short* W2T  = wsW + WOFF_W2T;
    const unsigned short* Wv1T = wsW + WOFF_WV1T;
    const unsigned short* W3aT = wsW + WOFF_W3AT;
    const unsigned short* W3bT = wsW + WOFF_W3BT;
    const unsigned short* W4T  = wsW + WOFF_W4T;
    const unsigned short* Wv2T = wsW + WOFF_WV2T;

    unsigned short* voxB = (unsigned short*)vox1acc;       // [V][256] bf16, in-place
    unsigned int* vox2acc = (unsigned int*)d_out;          // [V][256] — aliased with output

    hipMemsetAsync(vox1acc, 0, (size_t)NVOX * 128 * 4 + (size_t)NVOX * 4, stream); // +counts
    hipMemsetAsync(vox2acc, 0, (size_t)NVOX * 256 * 4, stream);

    prep_all<<<(W_TOTAL + 255) / 256, 256, 0, stream>>>(W1, W2, Wv1, W3, W4, Wv2, wsW);

    s_hist<<<(N_PTS + 255) / 256, 256, 0, stream>>>(idx, counts);
    s_scan<<<1, 1024, 0, stream>>>(counts, cursor);
    s_scatter<<<(N_PTS + 255) / 256, 256, 0, stream>>>(idx, cursor, order, svox);

    k1_points<<<K1_TILES, 256, 0, stream>>>(inp, order, svox, W1T, b1, W2T, b2,
                                            vox1acc, feat2seq);
    kvox2<<<NVOX / 64, 256, 0, stream>>>((const float*)vox1acc, Wv1T, bv1, W3aT, voxB);
    if (feat2seq)
        k3_lite<<<K3_TILES, 1024, 0, stream>>>(svox, feat2seq, voxB,
                                               W3bT, b3, W4T, b4, vox2acc);
    else
        k3_heavy<<<K3_TILES, 256, 0, stream>>>(inp, order, svox, W1T, b1, W2T, b2, voxB,
                                               W3bT, b3, W4T, b4, vox2acc);
    kvox_final<<<NVOX / 64, 256, 0, stream>>>((const float*)vox2acc, Wv2T, bv2,
                                              (float*)d_out);
}

// Round 13
// 537.846 us; speedup vs baseline: 1.0050x; 1.0050x over previous
//
#include <hip/hip_runtime.h>
#include <hip/hip_bf16.h>
#include <stdint.h>

#define N_PTS 500000
#define NVOX  65536
#define K1_TILES ((N_PTS + 127) / 128)   // 3907
#define K3_TILES ((N_PTS + 63) / 64)     // 7813  (M=64 per block, 1024 threads)

typedef __attribute__((ext_vector_type(8))) short bf16x8;   // 8 x bf16 (4 VGPRs)
typedef __attribute__((ext_vector_type(4))) float f32x4;    // MFMA accumulator

__device__ inline unsigned short f2bf(float f) {
    union { float f; unsigned int u; } v; v.f = f;
    unsigned int r = v.u + 0x7FFFu + ((v.u >> 16) & 1u);   // RNE
    return (unsigned short)(r >> 16);
}
__device__ inline float bf2f(unsigned short h) {
    return __uint_as_float((unsigned int)h << 16);
}

// 16-byte global->LDS DMA: LDS dest is wave-uniform base + lane*16 (HW adds
// the lane offset); global src is per-lane. Zero VGPR staging cost.
__device__ inline void gld16(const void* g, void* l) {
    __builtin_amdgcn_global_load_lds(
        (const __attribute__((address_space(1))) unsigned int*)g,
        (__attribute__((address_space(3))) unsigned int*)l, 16, 0, 0);
}

// --------- fused weight prep: all transposes into one contiguous region ----
#define WOFF_W1T   0
#define WOFF_W2T   2048
#define WOFF_WV1T  10240
#define WOFF_W3AT  26624
#define WOFF_W3BT  59392
#define WOFF_W4T   92160
#define WOFF_WV2T  157696
#define W_TOTAL    223232

__global__ void prep_all(const float* __restrict__ W1, const float* __restrict__ W2,
                         const float* __restrict__ Wv1, const float* __restrict__ W3,
                         const float* __restrict__ W4, const float* __restrict__ Wv2,
                         unsigned short* __restrict__ dst) {
    int i = blockIdx.x * 256 + threadIdx.x;
    if (i >= W_TOTAL) return;
    int o = i;
    if (o < 2048) {                       // W1T: [64][32], pad k
        int n = o >> 5, k = o & 31;
        dst[i] = (k < 6) ? f2bf(W1[k * 64 + n]) : (unsigned short)0;
    } else if ((o -= 2048) < 8192) {      // W2T: K=64 Nn=128
        int n = o >> 6, k = o & 63;
        dst[i] = f2bf(W2[k * 128 + n]);
    } else if ((o -= 8192) < 16384) {     // Wv1T: K=128 Nn=128
        int n = o >> 7, k = o & 127;
        dst[i] = f2bf(Wv1[k * 128 + n]);
    } else if ((o -= 16384) < 32768) {    // W3aT: K=128 Nn=256 k0=0
        int n = o >> 7, k = o & 127;
        dst[i] = f2bf(W3[k * 256 + n]);
    } else if ((o -= 32768) < 32768) {    // W3bT: K=128 Nn=256 k0=128
        int n = o >> 7, k = o & 127;
        dst[i] = f2bf(W3[(k + 128) * 256 + n]);
    } else if ((o -= 32768) < 65536) {    // W4T: K=256 Nn=256
        int n = o >> 8, k = o & 255;
        dst[i] = f2bf(W4[k * 256 + n]);
    } else {                              // Wv2T
        o -= 65536;
        int n = o >> 8, k = o & 255;
        dst[i] = f2bf(Wv2[k * 256 + n]);
    }
}

// ------------------------- counting sort by voxel --------------------------
__global__ void s_hist(const int* __restrict__ idx, unsigned int* __restrict__ counts) {
    int p = blockIdx.x * 256 + threadIdx.x;
    if (p < N_PTS) atomicAdd(&counts[idx[p]], 1u);
}

__global__ __launch_bounds__(1024) void s_scan(const unsigned int* __restrict__ counts,
                                               unsigned int* __restrict__ cursor) {
    __shared__ unsigned int sPart[1024];
    int t = threadIdx.x;
    unsigned int sum = 0;
    #pragma unroll 8
    for (int i = 0; i < 64; i++) sum += counts[t * 64 + i];
    sPart[t] = sum;
    __syncthreads();
    for (int d = 1; d < 1024; d <<= 1) {
        unsigned int add = (t >= d) ? sPart[t - d] : 0u;
        __syncthreads();
        sPart[t] += add;
        __syncthreads();
    }
    unsigned int run = (t == 0) ? 0u : sPart[t - 1];
    #pragma unroll 8
    for (int i = 0; i < 64; i++) {
        cursor[t * 64 + i] = run;
        run += counts[t * 64 + i];
    }
}

__global__ void s_scatter(const int* __restrict__ idx, unsigned int* __restrict__ cursor,
                          int* __restrict__ order, int* __restrict__ svox) {
    int p = blockIdx.x * 256 + threadIdx.x;
    if (p < N_PTS) {
        int v = idx[p];
        unsigned int pos = atomicAdd(&cursor[v], 1u);
        order[pos] = p;
        svox[pos] = v;
    }
}

// ---------------------------------------------------------------------------
// K1 v2 (operand-swapped epilogues): mfma(b,a) computes C^T whose fragment
// layout gives each thread 4 CONSECUTIVE COLUMNS of one row -> epilogue is
// one aligned uint2 LDS store instead of 4 scattered u16 stores.
// ---------------------------------------------------------------------------
__global__ __launch_bounds__(256, 4) void k1_points(
    const float* __restrict__ inp,
    const int* __restrict__ order, const int* __restrict__ svox,
    const unsigned short* __restrict__ W1T, const float* __restrict__ b1,
    const unsigned short* __restrict__ W2T, const float* __restrict__ b2,
    unsigned int* __restrict__ vox1acc,      // [V][128] fp32-as-uint (zeroed)
    unsigned short* __restrict__ feat2seq)   // [N][128] bf16 sorted (or null)
{
    __shared__ __align__(16) char sBuf[32 * 1024];
    __shared__ __align__(16) float sb1[64];
    __shared__ __align__(16) float sb2[128];
    __shared__ int   sVox[128];
    char* sIn = sBuf;                // [128][32] bf16, row 64B,  swz (m&3)<<4
    char* sF1 = sBuf + 8 * 1024;     // [128][64] bf16, row 128B, swz (m&7)<<4
    char* sF2 = sBuf;                // [128][128] bf16, row 256B, swz (m&7)<<4
    const f32x4 fzero = {0.f, 0.f, 0.f, 0.f};
    int tid = threadIdx.x;
    int pbase = blockIdx.x * 128;
    if (tid < 64)       sb1[tid] = b1[tid];
    else if (tid < 192) sb2[tid - 64] = b2[tid - 64];
    if (tid < 128) {
        int i = pbase + tid;
        int pt = -1, v = -1;
        if (i < N_PTS) { pt = order[i]; v = svox[i]; }
        sVox[tid] = v;
        uint4 g0 = {0u, 0u, 0u, 0u};
        if (pt >= 0) {
            const float* x = inp + (size_t)pt * 6;
            g0.x = (unsigned)f2bf(x[0]) | ((unsigned)f2bf(x[1]) << 16);
            g0.y = (unsigned)f2bf(x[2]) | ((unsigned)f2bf(x[3]) << 16);
            g0.z = (unsigned)f2bf(x[4]) | ((unsigned)f2bf(x[5]) << 16);
        }
        int swz = (tid & 3) << 4;
        char* row = sIn + tid * 64;
        uint4 z = {0u, 0u, 0u, 0u};
        *(uint4*)(row + (0  ^ swz)) = g0;
        *(uint4*)(row + (16 ^ swz)) = z;
        *(uint4*)(row + (32 ^ swz)) = z;
        *(uint4*)(row + (48 ^ swz)) = z;
    }
    __syncthreads();
    int wave = tid >> 6, lane = tid & 63, quad = lane >> 4, l16 = lane & 15;

    // GEMM1: [128][32]@[32][64]  (swapped)
    {
        f32x4 acc1[8];
        #pragma unroll
        for (int mt = 0; mt < 8; mt++) acc1[mt] = fzero;
        bf16x8 b = *(const bf16x8*)(W1T + (wave * 16 + l16) * 32 + quad * 8);
        #pragma unroll
        for (int mt = 0; mt < 8; mt++) {
            int m = mt * 16 + l16;
            bf16x8 a = *(const bf16x8*)(sIn + m * 64 + ((quad * 16) ^ ((m & 3) << 4)));
            acc1[mt] = __builtin_amdgcn_mfma_f32_16x16x32_bf16(b, a, acc1[mt], 0, 0, 0);
        }
        int nb = wave * 16 + quad * 4;
        float4 bi = *(const float4*)&sb1[nb];
        #pragma unroll
        for (int mt = 0; mt < 8; mt++) {
            int m = mt * 16 + l16;
            uint2 pk;
            pk.x = (unsigned)f2bf(fmaxf(acc1[mt][0] + bi.x, 0.f))
                 | ((unsigned)f2bf(fmaxf(acc1[mt][1] + bi.y, 0.f)) << 16);
            pk.y = (unsigned)f2bf(fmaxf(acc1[mt][2] + bi.z, 0.f))
                 | ((unsigned)f2bf(fmaxf(acc1[mt][3] + bi.w, 0.f)) << 16);
            *(uint2*)(sF1 + m * 128 + ((2 * nb) ^ ((m & 7) << 4))) = pk;
        }
    }
    __syncthreads();
    // GEMM2: [128][64]@[64][128]  (swapped)
    f32x4 acc2[2][8];
    #pragma unroll
    for (int j = 0; j < 2; j++)
        #pragma unroll
        for (int mt = 0; mt < 8; mt++) acc2[j][mt] = fzero;
    #pragma unroll
    for (int kt = 0; kt < 2; kt++) {
        bf16x8 b0 = *(const bf16x8*)(W2T + ((wave * 2 + 0) * 16 + l16) * 64 + kt * 32 + quad * 8);
        bf16x8 b1 = *(const bf16x8*)(W2T + ((wave * 2 + 1) * 16 + l16) * 64 + kt * 32 + quad * 8);
        #pragma unroll
        for (int mt = 0; mt < 8; mt++) {
            int m = mt * 16 + l16;
            bf16x8 a = *(const bf16x8*)(sF1 + m * 128 + ((kt * 64 + quad * 16) ^ ((m & 7) << 4)));
            acc2[0][mt] = __builtin_amdgcn_mfma_f32_16x16x32_bf16(b0, a, acc2[0][mt], 0, 0, 0);
            acc2[1][mt] = __builtin_amdgcn_mfma_f32_16x16x32_bf16(b1, a, acc2[1][mt], 0, 0, 0);
        }
    }
    __syncthreads();   // all sIn/sF1 reads done before sF2 overwrite
    #pragma unroll
    for (int j = 0; j < 2; j++) {
        int nb = (wave * 2 + j) * 16 + quad * 4;
        float4 bi = *(const float4*)&sb2[nb];
        #pragma unroll
        for (int mt = 0; mt < 8; mt++) {
            int m = mt * 16 + l16;
            uint2 pk;
            pk.x = (unsigned)f2bf(fmaxf(acc2[j][mt][0] + bi.x, 0.f))
                 | ((unsigned)f2bf(fmaxf(acc2[j][mt][1] + bi.y, 0.f)) << 16);
            pk.y = (unsigned)f2bf(fmaxf(acc2[j][mt][2] + bi.z, 0.f))
                 | ((unsigned)f2bf(fmaxf(acc2[j][mt][3] + bi.w, 0.f)) << 16);
            *(uint2*)(sF2 + m * 256 + ((2 * nb) ^ ((m & 7) << 4))) = pk;
        }
    }
    __syncthreads();
    // spill feat2 (sorted order) to global for k3_lite — coalesced uint4
    if (feat2seq) {
        #pragma unroll
        for (int it = 0; it < 8; it++) {
            int i = tid + 256 * it;
            int m = i >> 4, q = i & 15;
            if (pbase + m < N_PTS) {
                uint4 val = *(const uint4*)(sF2 + m * 256 + ((q * 16) ^ ((m & 7) << 4)));
                *(uint4*)(feat2seq + (size_t)(pbase + m) * 128 + q * 8) = val;
            }
        }
    }
    // segmented max walk; interior segments -> plain store
    {
        int c = tid & 127, r0 = (tid >> 7) * 64;
        int cur = -1; float vmax = 0.f; int segStart = r0;
        for (int r = r0; r < r0 + 64; r++) {
            int v = sVox[r];
            float f = bf2f(*(const unsigned short*)(sF2 + r * 256 + ((2 * c) ^ ((r & 7) << 4))));
            if (v != cur) {
                if (cur >= 0) {
                    if (segStart > r0)
                        vox1acc[(size_t)cur * 128 + c] = __float_as_uint(vmax);
                    else
                        atomicMax(vox1acc + (size_t)cur * 128 + c, __float_as_uint(vmax));
                }
                cur = v; vmax = f; segStart = r;
            } else vmax = fmaxf(vmax, f);
        }
        if (cur >= 0)
            atomicMax(vox1acc + (size_t)cur * 128 + c, __float_as_uint(vmax));
    }
}

// ---------------------------------------------------------------------------
// kvox2 (fused voxel chain): voxA = relu(vox1acc@Wv1+bv1);
// voxB = voxA@W3a (no bias/relu — b3 added in k3). voxB written IN-PLACE over
// vox1acc (block reads its 64 rows to LDS first; same byte range: 512 B/row).
// (R11 measured-best form — R12's swapped variant was noise-neutral.)
// ---------------------------------------------------------------------------
__global__ __launch_bounds__(256, 4) void kvox2(
    const float* __restrict__ in, const unsigned short* __restrict__ Wv1T,
    const float* __restrict__ bv1, const unsigned short* __restrict__ W3aT,
    unsigned short* __restrict__ voxB)     // [V][256] bf16, aliases `in`
{
    __shared__ __align__(16) char sA[64 * 256];   // [64][128] bf16 input
    __shared__ __align__(16) char sB[64 * 256];   // [64][128] bf16 voxA
    __shared__ float sb[128];
    const f32x4 fzero = {0.f, 0.f, 0.f, 0.f};
    int tid = threadIdx.x;
    int vb = blockIdx.x * 64;
    if (tid < 128) sb[tid] = bv1[tid];
    #pragma unroll
    for (int it = 0; it < 8; it++) {
        int i = tid + 256 * it;
        int m = i >> 5, kq = i & 31;
        float4 f = ((const float4*)(in + (size_t)(vb + m) * 128))[kq];
        uint2 p;
        p.x = (unsigned)f2bf(f.x) | ((unsigned)f2bf(f.y) << 16);
        p.y = (unsigned)f2bf(f.z) | ((unsigned)f2bf(f.w) << 16);
        *(uint2*)(sA + m * 256 + ((8 * kq) ^ ((m & 7) << 4))) = p;
    }
    __syncthreads();
    int wave = tid >> 6, lane = tid & 63, quad = lane >> 4, l16 = lane & 15;
    // GEMM A: voxA = relu([64][128]@[128][128] + bv1)
    {
        f32x4 acc[2][4];
        #pragma unroll
        for (int j = 0; j < 2; j++)
            #pragma unroll
            for (int mt = 0; mt < 4; mt++) acc[j][mt] = fzero;
        #pragma unroll
        for (int kt = 0; kt < 4; kt++) {
            bf16x8 a[4];
            #pragma unroll
            for (int mt = 0; mt < 4; mt++) {
                int m = mt * 16 + l16;
                a[mt] = *(const bf16x8*)(sA + m * 256 + ((kt * 64 + quad * 16) ^ ((m & 7) << 4)));
            }
            #pragma unroll
            for (int j = 0; j < 2; j++) {
                int n = (wave * 2 + j) * 16 + l16;
                bf16x8 b = *(const bf16x8*)(Wv1T + n * 128 + kt * 32 + quad * 8);
                #pragma unroll
                for (int mt = 0; mt < 4; mt++)
                    acc[j][mt] = __builtin_amdgcn_mfma_f32_16x16x32_bf16(a[mt], b, acc[j][mt], 0, 0, 0);
            }
        }
        #pragma unroll
        for (int j = 0; j < 2; j++) {
            int n = (wave * 2 + j) * 16 + l16;
            float bi = sb[n];
            #pragma unroll
            for (int mt = 0; mt < 4; mt++)
                #pragma unroll
                for (int r = 0; r < 4; r++) {
                    int m = mt * 16 + quad * 4 + r;
                    float v = fmaxf(acc[j][mt][r] + bi, 0.f);
                    *(unsigned short*)(sB + m * 256 + ((2 * n) ^ ((m & 7) << 4))) = f2bf(v);
                }
        }
    }
    __syncthreads();
    // GEMM B: voxB = voxA@[128][256]; no bias/relu
    {
        f32x4 acc[4][4];
        #pragma unroll
        for (int j = 0; j < 4; j++)
            #pragma unroll
            for (int mt = 0; mt < 4; mt++) acc[j][mt] = fzero;
        #pragma unroll
        for (int kt = 0; kt < 4; kt++) {
            bf16x8 a[4];
            #pragma unroll
            for (int mt = 0; mt < 4; mt++) {
                int m = mt * 16 + l16;
                a[mt] = *(const bf16x8*)(sB + m * 256 + ((kt * 64 + quad * 16) ^ ((m & 7) << 4)));
            }
            #pragma unroll
            for (int j = 0; j < 4; j++) {
                int n = (wave * 4 + j) * 16 + l16;
                bf16x8 b = *(const bf16x8*)(W3aT + n * 128 + kt * 32 + quad * 8);
                #pragma unroll
                for (int mt = 0; mt < 4; mt++)
                    acc[j][mt] = __builtin_amdgcn_mfma_f32_16x16x32_bf16(a[mt], b, acc[j][mt], 0, 0, 0);
            }
        }
        #pragma unroll
        for (int j = 0; j < 4; j++) {
            int n = (wave * 4 + j) * 16 + l16;
            #pragma unroll
            for (int mt = 0; mt < 4; mt++)
                #pragma unroll
                for (int r = 0; r < 4; r++) {
                    int m = mt * 16 + quad * 4 + r;
                    voxB[(size_t)(vb + m) * 256 + n] = f2bf(acc[j][mt][r]);
                }
        }
    }
}

// ---------------------------------------------------------------------------
// K3 LITE v12 (R11 winner): 64-pt tile, 1024 thr / 16 waves, acc[4]=16 AGPR,
// (1024,8) -> 32 waves/CU no spill; DMA staging w/ pre-swizzled source;
// T14 issue-early voxB rows 32-63; operand-swapped GEMM3'/GEMM4 epilogues
// (one uint2 RMW / store per mt). Measured 255-258 us.
// ---------------------------------------------------------------------------
__global__ __launch_bounds__(1024, 8) void k3_lite(
    const int* __restrict__ svox,
    const unsigned short* __restrict__ feat2seq, // [N][128] bf16 sorted
    const unsigned short* __restrict__ voxB,     // [V][256] bf16
    const unsigned short* __restrict__ W3bT, const float* __restrict__ b3,
    const unsigned short* __restrict__ W4T, const float* __restrict__ b4,
    unsigned int* __restrict__ vox2acc)          // [V][256] fp32-as-uint (zeroed)
{
    __shared__ __align__(16) char sBuf[32 * 1024];
    __shared__ __align__(16) float sb3[256];
    __shared__ __align__(16) float sb4[256];
    __shared__ int   sVox[64];
    char* sP  = sBuf;               // [64][256] bf16, row 512B: gather/feat4/feat5
    char* sF2 = sBuf + 16 * 1024;   // [64][128] bf16, row 256B: feat2 (dies post-GEMM3')
    const f32x4 fzero = {0.f, 0.f, 0.f, 0.f};
    int tid = threadIdx.x;
    int pbase = blockIdx.x * 64;
    int wave = tid >> 6, lane = tid & 63, quad = lane >> 4, l16 = lane & 15;
    if (tid < 256)      sb3[tid] = b3[tid];
    else if (tid < 512) sb4[tid - 256] = b4[tid - 256];
    if (tid < 64) {
        int i = pbase + tid;
        sVox[tid] = (i < N_PTS) ? svox[i] : -1;
    }
    // voxB rows 32-63 -> held register (1 uint4/thread, T14 issue-early).
    uint4 hv = {0u, 0u, 0u, 0u};
    int hm = 32 + (tid >> 5);          // row 32..63
    int hc = tid & 31;                 // 16B unit 0..31
    {
        int p = pbase + hm;
        if (p < N_PTS)
            hv = ((const uint4*)(voxB + (size_t)svox[p] * 256))[hc];
    }
    // voxB rows 0-31 -> sP low 16K via DMA; 16 chunks of 1KB, chunk q = wave.
    {
        int q = wave;
        int m = 2 * q + (lane >> 5);
        int u = lane & 31;
        int p = pbase + m; if (p >= N_PTS) p = N_PTS - 1;   // clamp: garbage rows dead via sVox
        gld16(voxB + (size_t)svox[p] * 256 + (size_t)(u ^ (m & 7)) * 8,
              sP + q * 1024);
    }
    // feat2 -> sF2 via DMA; chunk q = wave = 4 rows of 256B.
    {
        int q = wave;
        int m = 4 * q + (lane >> 4);
        int u = lane & 15;
        int p = pbase + m; if (p >= N_PTS) p = N_PTS - 1;
        gld16(feat2seq + (size_t)p * 128 + (size_t)(u ^ (m & 7)) * 8,
              sF2 + q * 1024);
    }
    __syncthreads();   // drains DMA (vmcnt) + sVox/sb visible

    int n = wave * 16 + l16;    // b-frag column index (per-lane)
    int nb = wave * 16 + quad * 4;   // this thread's 4 output columns (swapped C^T)

    // GEMM3': [64][128] @ [128][256]; swapped mfma(b,a)
    f32x4 acc[4];
    #pragma unroll
    for (int mt = 0; mt < 4; mt++) acc[mt] = fzero;
    #pragma unroll
    for (int kt = 0; kt < 4; kt++) {
        bf16x8 b = *(const bf16x8*)(W3bT + n * 128 + kt * 32 + quad * 8);
        #pragma unroll
        for (int mt = 0; mt < 4; mt++) {
            int m = mt * 16 + l16;
            bf16x8 a = *(const bf16x8*)(sF2 + m * 256 + ((kt * 64 + quad * 16) ^ ((m & 7) << 4)));
            acc[mt] = __builtin_amdgcn_mfma_f32_16x16x32_bf16(b, a, acc[mt], 0, 0, 0);
        }
    }
    __syncthreads();   // all sF2 reads done — its space becomes sP rows 32-63
    // write held voxB rows 32-63 into sP (dest-swizzled LDS write)
    *(uint4*)(sP + hm * 512 + ((hc * 16) ^ ((hm & 7) << 4))) = hv;
    __syncthreads();   // voxB rows 32-63 visible
    // feat4 = relu(acc + b3 + voxpart) -> sP in-place; one uint2 RMW per mt
    {
        float4 bi = *(const float4*)&sb3[nb];
        #pragma unroll
        for (int mt = 0; mt < 4; mt++) {
            int m = mt * 16 + l16;
            char* p = sP + m * 512 + ((2 * nb) ^ ((m & 7) << 4));
            uint2 vv = *(const uint2*)p;
            float v0 = fmaxf(acc[mt][0] + bi.x + bf2f((unsigned short)vv.x), 0.f);
            float v1 = fmaxf(acc[mt][1] + bi.y + bf2f((unsigned short)(vv.x >> 16)), 0.f);
            float v2 = fmaxf(acc[mt][2] + bi.z + bf2f((unsigned short)vv.y), 0.f);
            float v3 = fmaxf(acc[mt][3] + bi.w + bf2f((unsigned short)(vv.y >> 16)), 0.f);
            uint2 pk;
            pk.x = (unsigned)f2bf(v0) | ((unsigned)f2bf(v1) << 16);
            pk.y = (unsigned)f2bf(v2) | ((unsigned)f2bf(v3) << 16);
            *(uint2*)p = pk;
        }
    }
    __syncthreads();
    #pragma unroll
    for (int mt = 0; mt < 4; mt++) acc[mt] = fzero;
    // GEMM4: [64][256] @ [256][256]; swapped mfma(b,a)
    #pragma unroll 4
    for (int kt = 0; kt < 8; kt++) {
        bf16x8 b = *(const bf16x8*)(W4T + n * 256 + kt * 32 + quad * 8);
        #pragma unroll
        for (int mt = 0; mt < 4; mt++) {
            int m = mt * 16 + l16;
            bf16x8 a = *(const bf16x8*)(sP + m * 512 + ((kt * 64 + quad * 16) ^ ((m & 7) << 4)));
            acc[mt] = __builtin_amdgcn_mfma_f32_16x16x32_bf16(b, a, acc[mt], 0, 0, 0);
        }
    }
    __syncthreads();   // all feat4 reads done before feat5 overwrite
    // feat5 = relu(acc + b4) -> sP; one uint2 store per mt
    {
        float4 bi = *(const float4*)&sb4[nb];
        #pragma unroll
        for (int mt = 0; mt < 4; mt++) {
            int m = mt * 16 + l16;
            uint2 pk;
            pk.x = (unsigned)f2bf(fmaxf(acc[mt][0] + bi.x, 0.f))
                 | ((unsigned)f2bf(fmaxf(acc[mt][1] + bi.y, 0.f)) << 16);
            pk.y = (unsigned)f2bf(fmaxf(acc[mt][2] + bi.z, 0.f))
                 | ((unsigned)f2bf(fmaxf(acc[mt][3] + bi.w, 0.f)) << 16);
            *(uint2*)(sP + m * 512 + ((2 * nb) ^ ((m & 7) << 4))) = pk;
        }
    }
    __syncthreads();
    // segmented max: c = tid&255 (256 cols), four 16-row walkers per column;
    // interior segments -> plain store, boundary -> atomicMax (k1's pattern)
    {
        int c = tid & 255, r0 = (tid >> 8) * 16;
        int cur = -1; float vmax = 0.f; int segStart = r0;
        for (int r = r0; r < r0 + 16; r++) {
            int v = sVox[r];
            float f = bf2f(*(const unsigned short*)(sP + r * 512 + ((2 * c) ^ ((r & 7) << 4))));
            if (v != cur) {
                if (cur >= 0) {
                    if (segStart > r0)
                        vox2acc[(size_t)cur * 256 + c] = __float_as_uint(vmax);
                    else
                        atomicMax(vox2acc + (size_t)cur * 256 + c, __float_as_uint(vmax));
                }
                cur = v; vmax = f; segStart = r;
            } else vmax = fmaxf(vmax, f);
        }
        if (cur >= 0)
            atomicMax(vox2acc + (size_t)cur * 256 + c, __float_as_uint(vmax));
    }
}

// ---------------------------------------------------------------------------
// K3 v8 (FALLBACK, used only when workspace can't hold feat2seq):
// recomputes feat1/feat2 per tile. Unchanged from previous best.
// ---------------------------------------------------------------------------
__global__ __launch_bounds__(256, 3) void k3_heavy(
    const float* __restrict__ inp,
    const int* __restrict__ order, const int* __restrict__ svox,
    const unsigned short* __restrict__ W1T, const float* __restrict__ b1,
    const unsigned short* __restrict__ W2T, const float* __restrict__ b2,
    const unsigned short* __restrict__ voxB,     // [V][256] bf16
    const unsigned short* __restrict__ W3bT, const float* __restrict__ b3,
    const unsigned short* __restrict__ W4T, const float* __restrict__ b4,
    unsigned int* __restrict__ vox2acc)          // [V][256] fp32-as-uint (zeroed)
{
    __shared__ __align__(16) char sBuf[32 * 1024];
    __shared__ float sb1[64];
    __shared__ float sb2[128];
    __shared__ float sb3[256];
    __shared__ float sb4[256];
    __shared__ int   sVox[64];
    char* sF2 = sBuf;                 // [64][128] bf16, row 256B  (dies after GEMM3')
    char* sF1 = sBuf + 16 * 1024;     // [64][64]  bf16, row 128B  (phase 1-2)
    char* sIn = sBuf + 24 * 1024;     // [64][32]  bf16, row 64B   (phase 0-1)
    char* sP  = sBuf;                 // [64][256] bf16, row 512B  (gather onward)
    const f32x4 fzero = {0.f, 0.f, 0.f, 0.f};
    int tid = threadIdx.x;
    int pbase = blockIdx.x * 64;
    sb3[tid] = b3[tid];
    sb4[tid] = b4[tid];
    if (tid < 64)  sb1[tid] = b1[tid];
    if (tid < 128) sb2[tid] = b2[tid];
    if (tid < 64) {
        int i = pbase + tid;
        int pt = -1, v = -1;
        if (i < N_PTS) { pt = order[i]; v = svox[i]; }
        sVox[tid] = v;
        uint4 g0 = {0u, 0u, 0u, 0u};
        if (pt >= 0) {
            const float* x = inp + (size_t)pt * 6;
            g0.x = (unsigned)f2bf(x[0]) | ((unsigned)f2bf(x[1]) << 16);
            g0.y = (unsigned)f2bf(x[2]) | ((unsigned)f2bf(x[3]) << 16);
            g0.z = (unsigned)f2bf(x[4]) | ((unsigned)f2bf(x[5]) << 16);
        }
        int swz = (tid & 3) << 4;
        char* row = sIn + tid * 64;
        uint4 z = {0u, 0u, 0u, 0u};
        *(uint4*)(row + (0  ^ swz)) = g0;
        *(uint4*)(row + (16 ^ swz)) = z;
        *(uint4*)(row + (32 ^ swz)) = z;
        *(uint4*)(row + (48 ^ swz)) = z;
    }
    __syncthreads();
    int wave = tid >> 6, lane = tid & 63, quad = lane >> 4, l16 = lane & 15;

    // GEMM1: feat1 = relu([64][32]@[32][64] + b1); wave owns n-tile `wave`
    {
        f32x4 acc1[4];
        #pragma unroll
        for (int mt = 0; mt < 4; mt++) acc1[mt] = fzero;
        int n = wave * 16 + l16;
        bf16x8 b = *(const bf16x8*)(W1T + n * 32 + quad * 8);
        #pragma unroll
        for (int mt = 0; mt < 4; mt++) {
            int m = mt * 16 + l16;
            bf16x8 a = *(const bf16x8*)(sIn + m * 64 + ((quad * 16) ^ ((m & 3) << 4)));
            acc1[mt] = __builtin_amdgcn_mfma_f32_16x16x32_bf16(a, b, acc1[mt], 0, 0, 0);
        }
        float bias = sb1[n];
        #pragma unroll
        for (int mt = 0; mt < 4; mt++)
            #pragma unroll
            for (int r = 0; r < 4; r++) {
                int m = mt * 16 + quad * 4 + r;
                float v = fmaxf(acc1[mt][r] + bias, 0.f);
                *(unsigned short*)(sF1 + m * 128 + ((2 * n) ^ ((m & 7) << 4))) = f2bf(v);
            }
    }
    __syncthreads();
    // GEMM2: feat2 = relu([64][64]@[64][128] + b2); wave owns n-tiles 2w,2w+1
    {
        f32x4 acc2[2][4];
        #pragma unroll
        for (int j = 0; j < 2; j++)
            #pragma unroll
            for (int mt = 0; mt < 4; mt++) acc2[j][mt] = fzero;
        #pragma unroll
        for (int kt = 0; kt < 2; kt++) {
            bf16x8 b0 = *(const bf16x8*)(W2T + ((wave * 2 + 0) * 16 + l16) * 64 + kt * 32 + quad * 8);
            bf16x8 b1 = *(const bf16x8*)(W2T + ((wave * 2 + 1) * 16 + l16) * 64 + kt * 32 + quad * 8);
            #pragma unroll
            for (int mt = 0; mt < 4; mt++) {
                int m = mt * 16 + l16;
                bf16x8 a = *(const bf16x8*)(sF1 + m * 128 + ((kt * 64 + quad * 16) ^ ((m & 7) << 4)));
                acc2[0][mt] = __builtin_amdgcn_mfma_f32_16x16x32_bf16(a, b0, acc2[0][mt], 0, 0, 0);
                acc2[1][mt] = __builtin_amdgcn_mfma_f32_16x16x32_bf16(a, b1, acc2[1][mt], 0, 0, 0);
            }
        }
        #pragma unroll
        for (int j = 0; j < 2; j++) {
            int n = (wave * 2 + j) * 16 + l16;
            float bias = sb2[n];
            #pragma unroll
            for (int mt = 0; mt < 4; mt++)
                #pragma unroll
                for (int r = 0; r < 4; r++) {
                    int m = mt * 16 + quad * 4 + r;
                    float v = fmaxf(acc2[j][mt][r] + bias, 0.f);
                    *(unsigned short*)(sF2 + m * 256 + ((2 * n) ^ ((m & 7) << 4))) = f2bf(v);
                }
        }
    }
    __syncthreads();   // sF1/sIn dead; sF2 complete

    // GEMM3': [64][128] @ [128][256]; wave owns 4 n-tiles x 4 m-tiles
    f32x4 acc[4][4];
    #pragma unroll
    for (int j = 0; j < 4; j++)
        #pragma unroll
        for (int mt = 0; mt < 4; mt++) acc[j][mt] = fzero;
    #pragma unroll 1
    for (int kt = 0; kt < 4; kt++) {
        bf16x8 a[4];
        #pragma unroll
        for (int mt = 0; mt < 4; mt++) {
            int m = mt * 16 + l16;
            a[mt] = *(const bf16x8*)(sF2 + m * 256 + ((kt * 64 + quad * 16) ^ ((m & 7) << 4)));
        }
        #pragma unroll
        for (int j = 0; j < 4; j++) {
            int n = (wave * 4 + j) * 16 + l16;
            bf16x8 b = *(const bf16x8*)(W3bT + n * 128 + kt * 32 + quad * 8);
            #pragma unroll
            for (int mt = 0; mt < 4; mt++)
                acc[j][mt] = __builtin_amdgcn_mfma_f32_16x16x32_bf16(a[mt], b, acc[j][mt], 0, 0, 0);
        }
    }
    __syncthreads();   // sF2 reads complete — arena becomes sP
    // gather voxB rows -> sP [64][256] (sorted -> dedup, L2 hits)
    #pragma unroll
    for (int it = 0; it < 8; it++) {
        int i = tid + 256 * it;
        int m = i >> 5, c = i & 31;
        int vv = sVox[m];
        uint4 val = {0u, 0u, 0u, 0u};
        if (vv >= 0)
            val = ((const uint4*)(voxB + (size_t)vv * 256))[c];
        *(uint4*)(sP + m * 512 + ((c * 16) ^ ((m & 7) << 4))) = val;
    }
    __syncthreads();
    // feat4 = relu(acc + b3 + voxpart) -> sP in-place
    #pragma unroll
    for (int j = 0; j < 4; j++) {
        int n = (wave * 4 + j) * 16 + l16;
        float bias = sb3[n];
        #pragma unroll
        for (int mt = 0; mt < 4; mt++)
            #pragma unroll
            for (int r = 0; r < 4; r++) {
                int m = mt * 16 + quad * 4 + r;
                char* p = sP + m * 512 + ((2 * n) ^ ((m & 7) << 4));
                float vox = bf2f(*(const unsigned short*)p);
                float v = fmaxf(acc[j][mt][r] + bias + vox, 0.f);
                *(unsigned short*)p = f2bf(v);
            }
    }
    __syncthreads();
    #pragma unroll
    for (int j = 0; j < 4; j++)
        #pragma unroll
        for (int mt = 0; mt < 4; mt++) acc[j][mt] = fzero;
    // GEMM4: [64][256] @ [256][256]
    #pragma unroll 1
    for (int kt = 0; kt < 8; kt++) {
        bf16x8 a[4];
        #pragma unroll
        for (int mt = 0; mt < 4; mt++) {
            int m = mt * 16 + l16;
            a[mt] = *(const bf16x8*)(sP + m * 512 + ((kt * 64 + quad * 16) ^ ((m & 7) << 4)));
        }
        #pragma unroll
        for (int j = 0; j < 4; j++) {
            int n = (wave * 4 + j) * 16 + l16;
            bf16x8 b = *(const bf16x8*)(W4T + n * 256 + kt * 32 + quad * 8);
            #pragma unroll
            for (int mt = 0; mt < 4; mt++)
                acc[j][mt] = __builtin_amdgcn_mfma_f32_16x16x32_bf16(a[mt], b, acc[j][mt], 0, 0, 0);
        }
    }
    __syncthreads();   // all feat4 reads done before feat5 overwrite
    // feat5 = relu(acc + b4) -> sP
    #pragma unroll
    for (int j = 0; j < 4; j++) {
        int n = (wave * 4 + j) * 16 + l16;
        float bias = sb4[n];
        #pragma unroll
        for (int mt = 0; mt < 4; mt++)
            #pragma unroll
            for (int r = 0; r < 4; r++) {
                int m = mt * 16 + quad * 4 + r;
                float v = fmaxf(acc[j][mt][r] + bias, 0.f);
                *(unsigned short*)(sP + m * 512 + ((2 * n) ^ ((m & 7) << 4))) = f2bf(v);
            }
    }
    __syncthreads();
    // segmented max: c = tid (256 cols), 64 rows; interior -> plain store
    {
        int c = tid;
        int cur = -1; float vmax = 0.f; int segStart = 0;
        for (int r = 0; r < 64; r++) {
            int v = sVox[r];
            float f = bf2f(*(const unsigned short*)(sP + r * 512 + ((2 * c) ^ ((r & 7) << 4))));
            if (v != cur) {
                if (cur >= 0) {
                    if (segStart > 0)
                        vox2acc[(size_t)cur * 256 + c] = __float_as_uint(vmax);
                    else
                        atomicMax(vox2acc + (size_t)cur * 256 + c, __float_as_uint(vmax));
                }
                cur = v; vmax = f; segStart = r;
            } else vmax = fmaxf(vmax, f);
        }
        if (cur >= 0)
            atomicMax(vox2acc + (size_t)cur * 256 + c, __float_as_uint(vmax));
    }
}

// ---------------------------------------------------------------------------
// Final voxel MLP: out = relu(in @ Wv2 + bv2); safe for in == out.
// (R11 measured-best form.)
// ---------------------------------------------------------------------------
__global__ __launch_bounds__(256, 4) void kvox_final(
    const float* __restrict__ in, const unsigned short* __restrict__ WT,
    const float* __restrict__ bias, float* __restrict__ outp)
{
    __shared__ __align__(16) char sA[64 * 512];
    __shared__ float sb[256];
    const f32x4 fzero = {0.f, 0.f, 0.f, 0.f};
    int tid = threadIdx.x;
    int vb = blockIdx.x * 64;
    sb[tid] = bias[tid];
    #pragma unroll
    for (int it = 0; it < 16; it++) {
        int i = tid + 256 * it;
        int m = i >> 6, kq = i & 63;
        float4 f = ((const float4*)(in + (size_t)(vb + m) * 256))[kq];
        uint2 p;
        p.x = (unsigned)f2bf(f.x) | ((unsigned)f2bf(f.y) << 16);
        p.y = (unsigned)f2bf(f.z) | ((unsigned)f2bf(f.w) << 16);
        *(uint2*)(sA + m * 512 + ((8 * kq) ^ ((m & 7) << 4))) = p;
    }
    __syncthreads();
    int wave = tid >> 6, lane = tid & 63, quad = lane >> 4, l16 = lane & 15;
    f32x4 acc[4][4];
    #pragma unroll
    for (int j = 0; j < 4; j++)
        #pragma unroll
        for (int mt = 0; mt < 4; mt++) acc[j][mt] = fzero;
    #pragma unroll 1
    for (int kt = 0; kt < 8; kt++) {
        bf16x8 a[4];
        #pragma unroll
        for (int mt = 0; mt < 4; mt++) {
            int m = mt * 16 + l16;
            a[mt] = *(const bf16x8*)(sA + m * 512 + ((kt * 64 + quad * 16) ^ ((m & 7) << 4)));
        }
        #pragma unroll
        for (int j = 0; j < 4; j++) {
            int n = (wave * 4 + j) * 16 + l16;
            bf16x8 b = *(const bf16x8*)(WT + n * 256 + kt * 32 + quad * 8);
            #pragma unroll
            for (int mt = 0; mt < 4; mt++)
                acc[j][mt] = __builtin_amdgcn_mfma_f32_16x16x32_bf16(a[mt], b, acc[j][mt], 0, 0, 0);
        }
    }
    #pragma unroll
    for (int j = 0; j < 4; j++) {
        int n = (wave * 4 + j) * 16 + l16;
        float bi = sb[n];
        #pragma unroll
        for (int mt = 0; mt < 4; mt++)
            #pragma unroll
            for (int r = 0; r < 4; r++) {
                int m = mt * 16 + quad * 4 + r;
                outp[(size_t)(vb + m) * 256 + n] = fmaxf(acc[j][mt][r] + bi, 0.f);
            }
    }
}

extern "C" void kernel_launch(void* const* d_in, const int* in_sizes, int n_in,
                              void* d_out, int out_size, void* d_ws, size_t ws_size,
                              hipStream_t stream) {
    const float* inp  = (const float*)d_in[0];
    const int*   idx  = (const int*)d_in[1];
    const float* W1   = (const float*)d_in[2];
    const float* b1   = (const float*)d_in[3];
    const float* W2   = (const float*)d_in[4];
    const float* b2   = (const float*)d_in[5];
    const float* Wv1  = (const float*)d_in[6];
    const float* bv1  = (const float*)d_in[7];
    const float* W3   = (const float*)d_in[8];
    const float* b3   = (const float*)d_in[9];
    const float* W4   = (const float*)d_in[10];
    const float* b4   = (const float*)d_in[11];
    const float* Wv2  = (const float*)d_in[12];
    const float* bv2  = (const float*)d_in[13];

    // workspace layout — base ~38 MB; +122 MB feat2seq when it fits
    char* ws = (char*)d_ws;
    size_t off = 0;
    unsigned int*   vox1acc = (unsigned int*)(ws + off);   off += (size_t)NVOX * 128 * 4;  // 32 MB
    unsigned int*   counts  = (unsigned int*)(ws + off);   off += (size_t)NVOX * 4;
    unsigned int*   cursor  = (unsigned int*)(ws + off);   off += (size_t)NVOX * 4;
    int*            order   = (int*)(ws + off);            off += (size_t)N_PTS * 4;
    int*            svox    = (int*)(ws + off);            off += (size_t)N_PTS * 4;
    unsigned short* wsW     = (unsigned short*)(ws + off); off += (size_t)W_TOTAL * 2;

    unsigned short* feat2seq = nullptr;                    // [N][128] bf16 sorted
    if (ws_size >= off + (size_t)N_PTS * 128 * 2)
        feat2seq = (unsigned short*)(ws + off);

    const unsigned short* W1T  = wsW + WOFF_W1T;
    const unsigned short* W2T  = wsW + WOFF_W2T;
    const unsigned short* Wv1T = wsW + WOFF_WV1T;
    const unsigned short* W3aT = wsW + WOFF_W3AT;
    const unsigned short* W3bT = wsW + WOFF_W3BT;
    const unsigned short* W4T  = wsW + WOFF_W4T;
    const unsigned short* Wv2T = wsW + WOFF_WV2T;

    unsigned short* voxB = (unsigned short*)vox1acc;       // [V][256] bf16, in-place
    unsigned int* vox2acc = (unsigned int*)d_out;          // [V][256] — aliased with output

    hipMemsetAsync(vox1acc, 0, (size_t)NVOX * 128 * 4 + (size_t)NVOX * 4, stream); // +counts
    hipMemsetAsync(vox2acc, 0, (size_t)NVOX * 256 * 4, stream);

    prep_all<<<(W_TOTAL + 255) / 256, 256, 0, stream>>>(W1, W2, Wv1, W3, W4, Wv2, wsW);

    s_hist<<<(N_PTS + 255) / 256, 256, 0, stream>>>(idx, counts);
    s_scan<<<1, 1024, 0, stream>>>(counts, cursor);
    s_scatter<<<(N_PTS + 255) / 256, 256, 0, stream>>>(idx, cursor, order, svox);

    k1_points<<<K1_TILES, 256, 0, stream>>>(inp, order, svox, W1T, b1, W2T, b2,
                                            vox1acc, feat2seq);
    kvox2<<<NVOX / 64, 256, 0, stream>>>((const float*)vox1acc, Wv1T, bv1, W3aT, voxB);
    if (feat2seq)
        k3_lite<<<K3_TILES, 1024, 0, stream>>>(svox, feat2seq, voxB,
                                               W3bT, b3, W4T, b4, vox2acc);
    else
        k3_heavy<<<K3_TILES, 256, 0, stream>>>(inp, order, svox, W1T, b1, W2T, b2, voxB,
                                               W3bT, b3, W4T, b4, vox2acc);
    kvox_final<<<NVOX / 64, 256, 0, stream>>>((const float*)vox2acc, Wv2T, bv2,
                                              (float*)d_out);
}

// Round 14
// 534.802 us; speedup vs baseline: 1.0107x; 1.0057x over previous
//
#include <hip/hip_runtime.h>
#include <hip/hip_bf16.h>
#include <stdint.h>

#define N_PTS 500000
#define NVOX  65536
#define K1_TILES ((N_PTS + 127) / 128)   // 3907
#define K3_TILES ((N_PTS + 63) / 64)     // 7813  (M=64 per block, 1024 threads)

typedef __attribute__((ext_vector_type(8))) short bf16x8;   // 8 x bf16 (4 VGPRs)
typedef __attribute__((ext_vector_type(4))) float f32x4;    // MFMA accumulator

__device__ inline unsigned short f2bf(float f) {
    union { float f; unsigned int u; } v; v.f = f;
    unsigned int r = v.u + 0x7FFFu + ((v.u >> 16) & 1u);   // RNE
    return (unsigned short)(r >> 16);
}
__device__ inline float bf2f(unsigned short h) {
    return __uint_as_float((unsigned int)h << 16);
}

// 16-byte global->LDS DMA: LDS dest is wave-uniform base + lane*16 (HW adds
// the lane offset); global src is per-lane. Zero VGPR staging cost.
__device__ inline void gld16(const void* g, void* l) {
    __builtin_amdgcn_global_load_lds(
        (const __attribute__((address_space(1))) unsigned int*)g,
        (__attribute__((address_space(3))) unsigned int*)l, 16, 0, 0);
}

// --------- fused weight prep: all transposes into one contiguous region ----
#define WOFF_W1T   0
#define WOFF_W2T   2048
#define WOFF_WV1T  10240
#define WOFF_W3AT  26624
#define WOFF_W3BT  59392
#define WOFF_W4T   92160
#define WOFF_WV2T  157696
#define W_TOTAL    223232

__global__ void prep_all(const float* __restrict__ W1, const float* __restrict__ W2,
                         const float* __restrict__ Wv1, const float* __restrict__ W3,
                         const float* __restrict__ W4, const float* __restrict__ Wv2,
                         unsigned short* __restrict__ dst) {
    int i = blockIdx.x * 256 + threadIdx.x;
    if (i >= W_TOTAL) return;
    int o = i;
    if (o < 2048) {                       // W1T: [64][32], pad k
        int n = o >> 5, k = o & 31;
        dst[i] = (k < 6) ? f2bf(W1[k * 64 + n]) : (unsigned short)0;
    } else if ((o -= 2048) < 8192) {      // W2T: K=64 Nn=128
        int n = o >> 6, k = o & 63;
        dst[i] = f2bf(W2[k * 128 + n]);
    } else if ((o -= 8192) < 16384) {     // Wv1T: K=128 Nn=128
        int n = o >> 7, k = o & 127;
        dst[i] = f2bf(Wv1[k * 128 + n]);
    } else if ((o -= 16384) < 32768) {    // W3aT: K=128 Nn=256 k0=0
        int n = o >> 7, k = o & 127;
        dst[i] = f2bf(W3[k * 256 + n]);
    } else if ((o -= 32768) < 32768) {    // W3bT: K=128 Nn=256 k0=128
        int n = o >> 7, k = o & 127;
        dst[i] = f2bf(W3[(k + 128) * 256 + n]);
    } else if ((o -= 32768) < 65536) {    // W4T: K=256 Nn=256
        int n = o >> 8, k = o & 255;
        dst[i] = f2bf(W4[k * 256 + n]);
    } else {                              // Wv2T
        o -= 65536;
        int n = o >> 8, k = o & 255;
        dst[i] = f2bf(Wv2[k * 256 + n]);
    }
}

// ------------------------- counting sort by voxel --------------------------
__global__ void s_hist(const int* __restrict__ idx, unsigned int* __restrict__ counts) {
    int p = blockIdx.x * 256 + threadIdx.x;
    if (p < N_PTS) atomicAdd(&counts[idx[p]], 1u);
}

__global__ __launch_bounds__(1024) void s_scan(const unsigned int* __restrict__ counts,
                                               unsigned int* __restrict__ cursor) {
    __shared__ unsigned int sPart[1024];
    int t = threadIdx.x;
    unsigned int sum = 0;
    #pragma unroll 8
    for (int i = 0; i < 64; i++) sum += counts[t * 64 + i];
    sPart[t] = sum;
    __syncthreads();
    for (int d = 1; d < 1024; d <<= 1) {
        unsigned int add = (t >= d) ? sPart[t - d] : 0u;
        __syncthreads();
        sPart[t] += add;
        __syncthreads();
    }
    unsigned int run = (t == 0) ? 0u : sPart[t - 1];
    #pragma unroll 8
    for (int i = 0; i < 64; i++) {
        cursor[t * 64 + i] = run;
        run += counts[t * 64 + i];
    }
}

__global__ void s_scatter(const int* __restrict__ idx, unsigned int* __restrict__ cursor,
                          int* __restrict__ order, int* __restrict__ svox) {
    int p = blockIdx.x * 256 + threadIdx.x;
    if (p < N_PTS) {
        int v = idx[p];
        unsigned int pos = atomicAdd(&cursor[v], 1u);
        order[pos] = p;
        svox[pos] = v;
    }
}

// ---------------------------------------------------------------------------
// K1 v3: 512 threads (8 waves), wave (mh,nw)=(w>>2,w&3) owns half the
// m-tiles -> acc1[4]=16 AGPR, acc2[2][4]=32 AGPR (halved from v2).
// (512,8) -> 4 blocks x 8 waves = 32 waves/CU (100%, was 50%); live regs
// ~58 <= 64 cap, no spill (k3-R4 playbook). Swapped-C^T epilogues kept.
// ---------------------------------------------------------------------------
__global__ __launch_bounds__(512, 8) void k1_points(
    const float* __restrict__ inp,
    const int* __restrict__ order, const int* __restrict__ svox,
    const unsigned short* __restrict__ W1T, const float* __restrict__ b1,
    const unsigned short* __restrict__ W2T, const float* __restrict__ b2,
    unsigned int* __restrict__ vox1acc,      // [V][128] fp32-as-uint (zeroed)
    unsigned short* __restrict__ feat2seq)   // [N][128] bf16 sorted (or null)
{
    __shared__ __align__(16) char sBuf[32 * 1024];
    __shared__ __align__(16) float sb1[64];
    __shared__ __align__(16) float sb2[128];
    __shared__ int   sVox[128];
    char* sIn = sBuf;                // [128][32] bf16, row 64B,  swz (m&3)<<4
    char* sF1 = sBuf + 8 * 1024;     // [128][64] bf16, row 128B, swz (m&7)<<4
    char* sF2 = sBuf;                // [128][128] bf16, row 256B, swz (m&7)<<4
    const f32x4 fzero = {0.f, 0.f, 0.f, 0.f};
    int tid = threadIdx.x;
    int pbase = blockIdx.x * 128;
    if (tid < 64)       sb1[tid] = b1[tid];
    else if (tid < 192) sb2[tid - 64] = b2[tid - 64];
    if (tid < 128) {
        int i = pbase + tid;
        int pt = -1, v = -1;
        if (i < N_PTS) { pt = order[i]; v = svox[i]; }
        sVox[tid] = v;
        uint4 g0 = {0u, 0u, 0u, 0u};
        if (pt >= 0) {
            const float* x = inp + (size_t)pt * 6;
            g0.x = (unsigned)f2bf(x[0]) | ((unsigned)f2bf(x[1]) << 16);
            g0.y = (unsigned)f2bf(x[2]) | ((unsigned)f2bf(x[3]) << 16);
            g0.z = (unsigned)f2bf(x[4]) | ((unsigned)f2bf(x[5]) << 16);
        }
        int swz = (tid & 3) << 4;
        char* row = sIn + tid * 64;
        uint4 z = {0u, 0u, 0u, 0u};
        *(uint4*)(row + (0  ^ swz)) = g0;
        *(uint4*)(row + (16 ^ swz)) = z;
        *(uint4*)(row + (32 ^ swz)) = z;
        *(uint4*)(row + (48 ^ swz)) = z;
    }
    __syncthreads();
    int wave = tid >> 6, lane = tid & 63, quad = lane >> 4, l16 = lane & 15;
    int nw = wave & 3, mh = wave >> 2;   // n-tile group, m-half

    // GEMM1: [128][32]@[32][64]  (swapped; wave owns n-tile nw, m-tiles mh*4+mt)
    {
        f32x4 acc1[4];
        #pragma unroll
        for (int mt = 0; mt < 4; mt++) acc1[mt] = fzero;
        bf16x8 b = *(const bf16x8*)(W1T + (nw * 16 + l16) * 32 + quad * 8);
        #pragma unroll
        for (int mt = 0; mt < 4; mt++) {
            int m = (mh * 4 + mt) * 16 + l16;
            bf16x8 a = *(const bf16x8*)(sIn + m * 64 + ((quad * 16) ^ ((m & 3) << 4)));
            acc1[mt] = __builtin_amdgcn_mfma_f32_16x16x32_bf16(b, a, acc1[mt], 0, 0, 0);
        }
        int nb = nw * 16 + quad * 4;
        float4 bi = *(const float4*)&sb1[nb];
        #pragma unroll
        for (int mt = 0; mt < 4; mt++) {
            int m = (mh * 4 + mt) * 16 + l16;
            uint2 pk;
            pk.x = (unsigned)f2bf(fmaxf(acc1[mt][0] + bi.x, 0.f))
                 | ((unsigned)f2bf(fmaxf(acc1[mt][1] + bi.y, 0.f)) << 16);
            pk.y = (unsigned)f2bf(fmaxf(acc1[mt][2] + bi.z, 0.f))
                 | ((unsigned)f2bf(fmaxf(acc1[mt][3] + bi.w, 0.f)) << 16);
            *(uint2*)(sF1 + m * 128 + ((2 * nb) ^ ((m & 7) << 4))) = pk;
        }
    }
    __syncthreads();
    // GEMM2: [128][64]@[64][128]  (swapped; wave owns n-tiles 2nw,2nw+1)
    f32x4 acc2[2][4];
    #pragma unroll
    for (int j = 0; j < 2; j++)
        #pragma unroll
        for (int mt = 0; mt < 4; mt++) acc2[j][mt] = fzero;
    #pragma unroll
    for (int kt = 0; kt < 2; kt++) {
        bf16x8 b0 = *(const bf16x8*)(W2T + ((nw * 2 + 0) * 16 + l16) * 64 + kt * 32 + quad * 8);
        bf16x8 b1 = *(const bf16x8*)(W2T + ((nw * 2 + 1) * 16 + l16) * 64 + kt * 32 + quad * 8);
        #pragma unroll
        for (int mt = 0; mt < 4; mt++) {
            int m = (mh * 4 + mt) * 16 + l16;
            bf16x8 a = *(const bf16x8*)(sF1 + m * 128 + ((kt * 64 + quad * 16) ^ ((m & 7) << 4)));
            acc2[0][mt] = __builtin_amdgcn_mfma_f32_16x16x32_bf16(b0, a, acc2[0][mt], 0, 0, 0);
            acc2[1][mt] = __builtin_amdgcn_mfma_f32_16x16x32_bf16(b1, a, acc2[1][mt], 0, 0, 0);
        }
    }
    __syncthreads();   // all sIn/sF1 reads done before sF2 overwrite
    #pragma unroll
    for (int j = 0; j < 2; j++) {
        int nb = (nw * 2 + j) * 16 + quad * 4;
        float4 bi = *(const float4*)&sb2[nb];
        #pragma unroll
        for (int mt = 0; mt < 4; mt++) {
            int m = (mh * 4 + mt) * 16 + l16;
            uint2 pk;
            pk.x = (unsigned)f2bf(fmaxf(acc2[j][mt][0] + bi.x, 0.f))
                 | ((unsigned)f2bf(fmaxf(acc2[j][mt][1] + bi.y, 0.f)) << 16);
            pk.y = (unsigned)f2bf(fmaxf(acc2[j][mt][2] + bi.z, 0.f))
                 | ((unsigned)f2bf(fmaxf(acc2[j][mt][3] + bi.w, 0.f)) << 16);
            *(uint2*)(sF2 + m * 256 + ((2 * nb) ^ ((m & 7) << 4))) = pk;
        }
    }
    __syncthreads();
    // spill feat2 (sorted order) to global for k3_lite — coalesced uint4
    if (feat2seq) {
        #pragma unroll
        for (int it = 0; it < 4; it++) {
            int i = tid + 512 * it;
            int m = i >> 4, q = i & 15;
            if (pbase + m < N_PTS) {
                uint4 val = *(const uint4*)(sF2 + m * 256 + ((q * 16) ^ ((m & 7) << 4)));
                *(uint4*)(feat2seq + (size_t)(pbase + m) * 128 + q * 8) = val;
            }
        }
    }
    // segmented max walk; 4 walkers x 32 rows per column;
    // interior segments -> plain store
    {
        int c = tid & 127, r0 = (tid >> 7) * 32;
        int cur = -1; float vmax = 0.f; int segStart = r0;
        for (int r = r0; r < r0 + 32; r++) {
            int v = sVox[r];
            float f = bf2f(*(const unsigned short*)(sF2 + r * 256 + ((2 * c) ^ ((r & 7) << 4))));
            if (v != cur) {
                if (cur >= 0) {
                    if (segStart > r0)
                        vox1acc[(size_t)cur * 128 + c] = __float_as_uint(vmax);
                    else
                        atomicMax(vox1acc + (size_t)cur * 128 + c, __float_as_uint(vmax));
                }
                cur = v; vmax = f; segStart = r;
            } else vmax = fmaxf(vmax, f);
        }
        if (cur >= 0)
            atomicMax(vox1acc + (size_t)cur * 128 + c, __float_as_uint(vmax));
    }
}

// ---------------------------------------------------------------------------
// kvox2 (fused voxel chain): voxA = relu(vox1acc@Wv1+bv1);
// voxB = voxA@W3a (no bias/relu — b3 added in k3). voxB written IN-PLACE over
// vox1acc (block reads its 64 rows to LDS first; same byte range: 512 B/row).
// ---------------------------------------------------------------------------
__global__ __launch_bounds__(256, 4) void kvox2(
    const float* __restrict__ in, const unsigned short* __restrict__ Wv1T,
    const float* __restrict__ bv1, const unsigned short* __restrict__ W3aT,
    unsigned short* __restrict__ voxB)     // [V][256] bf16, aliases `in`
{
    __shared__ __align__(16) char sA[64 * 256];   // [64][128] bf16 input
    __shared__ __align__(16) char sB[64 * 256];   // [64][128] bf16 voxA
    __shared__ float sb[128];
    const f32x4 fzero = {0.f, 0.f, 0.f, 0.f};
    int tid = threadIdx.x;
    int vb = blockIdx.x * 64;
    if (tid < 128) sb[tid] = bv1[tid];
    #pragma unroll
    for (int it = 0; it < 8; it++) {
        int i = tid + 256 * it;
        int m = i >> 5, kq = i & 31;
        float4 f = ((const float4*)(in + (size_t)(vb + m) * 128))[kq];
        uint2 p;
        p.x = (unsigned)f2bf(f.x) | ((unsigned)f2bf(f.y) << 16);
        p.y = (unsigned)f2bf(f.z) | ((unsigned)f2bf(f.w) << 16);
        *(uint2*)(sA + m * 256 + ((8 * kq) ^ ((m & 7) << 4))) = p;
    }
    __syncthreads();
    int wave = tid >> 6, lane = tid & 63, quad = lane >> 4, l16 = lane & 15;
    // GEMM A: voxA = relu([64][128]@[128][128] + bv1)
    {
        f32x4 acc[2][4];
        #pragma unroll
        for (int j = 0; j < 2; j++)
            #pragma unroll
            for (int mt = 0; mt < 4; mt++) acc[j][mt] = fzero;
        #pragma unroll
        for (int kt = 0; kt < 4; kt++) {
            bf16x8 a[4];
            #pragma unroll
            for (int mt = 0; mt < 4; mt++) {
                int m = mt * 16 + l16;
                a[mt] = *(const bf16x8*)(sA + m * 256 + ((kt * 64 + quad * 16) ^ ((m & 7) << 4)));
            }
            #pragma unroll
            for (int j = 0; j < 2; j++) {
                int n = (wave * 2 + j) * 16 + l16;
                bf16x8 b = *(const bf16x8*)(Wv1T + n * 128 + kt * 32 + quad * 8);
                #pragma unroll
                for (int mt = 0; mt < 4; mt++)
                    acc[j][mt] = __builtin_amdgcn_mfma_f32_16x16x32_bf16(a[mt], b, acc[j][mt], 0, 0, 0);
            }
        }
        #pragma unroll
        for (int j = 0; j < 2; j++) {
            int n = (wave * 2 + j) * 16 + l16;
            float bi = sb[n];
            #pragma unroll
            for (int mt = 0; mt < 4; mt++)
                #pragma unroll
                for (int r = 0; r < 4; r++) {
                    int m = mt * 16 + quad * 4 + r;
                    float v = fmaxf(acc[j][mt][r] + bi, 0.f);
                    *(unsigned short*)(sB + m * 256 + ((2 * n) ^ ((m & 7) << 4))) = f2bf(v);
                }
        }
    }
    __syncthreads();
    // GEMM B: voxB = voxA@[128][256]; no bias/relu
    {
        f32x4 acc[4][4];
        #pragma unroll
        for (int j = 0; j < 4; j++)
            #pragma unroll
            for (int mt = 0; mt < 4; mt++) acc[j][mt] = fzero;
        #pragma unroll
        for (int kt = 0; kt < 4; kt++) {
            bf16x8 a[4];
            #pragma unroll
            for (int mt = 0; mt < 4; mt++) {
                int m = mt * 16 + l16;
                a[mt] = *(const bf16x8*)(sB + m * 256 + ((kt * 64 + quad * 16) ^ ((m & 7) << 4)));
            }
            #pragma unroll
            for (int j = 0; j < 4; j++) {
                int n = (wave * 4 + j) * 16 + l16;
                bf16x8 b = *(const bf16x8*)(W3aT + n * 128 + kt * 32 + quad * 8);
                #pragma unroll
                for (int mt = 0; mt < 4; mt++)
                    acc[j][mt] = __builtin_amdgcn_mfma_f32_16x16x32_bf16(a[mt], b, acc[j][mt], 0, 0, 0);
            }
        }
        #pragma unroll
        for (int j = 0; j < 4; j++) {
            int n = (wave * 4 + j) * 16 + l16;
            #pragma unroll
            for (int mt = 0; mt < 4; mt++)
                #pragma unroll
                for (int r = 0; r < 4; r++) {
                    int m = mt * 16 + quad * 4 + r;
                    voxB[(size_t)(vb + m) * 256 + n] = f2bf(acc[j][mt][r]);
                }
        }
    }
}

// ---------------------------------------------------------------------------
// K3 LITE v12 (R11 winner): 64-pt tile, 1024 thr / 16 waves, acc[4]=16 AGPR,
// (1024,8) -> 32 waves/CU no spill; DMA staging w/ pre-swizzled source;
// T14 issue-early voxB rows 32-63; operand-swapped GEMM3'/GEMM4 epilogues
// (one uint2 RMW / store per mt). Measured 255-258 us.
// ---------------------------------------------------------------------------
__global__ __launch_bounds__(1024, 8) void k3_lite(
    const int* __restrict__ svox,
    const unsigned short* __restrict__ feat2seq, // [N][128] bf16 sorted
    const unsigned short* __restrict__ voxB,     // [V][256] bf16
    const unsigned short* __restrict__ W3bT, const float* __restrict__ b3,
    const unsigned short* __restrict__ W4T, const float* __restrict__ b4,
    unsigned int* __restrict__ vox2acc)          // [V][256] fp32-as-uint (zeroed)
{
    __shared__ __align__(16) char sBuf[32 * 1024];
    __shared__ __align__(16) float sb3[256];
    __shared__ __align__(16) float sb4[256];
    __shared__ int   sVox[64];
    char* sP  = sBuf;               // [64][256] bf16, row 512B: gather/feat4/feat5
    char* sF2 = sBuf + 16 * 1024;   // [64][128] bf16, row 256B: feat2 (dies post-GEMM3')
    const f32x4 fzero = {0.f, 0.f, 0.f, 0.f};
    int tid = threadIdx.x;
    int pbase = blockIdx.x * 64;
    int wave = tid >> 6, lane = tid & 63, quad = lane >> 4, l16 = lane & 15;
    if (tid < 256)      sb3[tid] = b3[tid];
    else if (tid < 512) sb4[tid - 256] = b4[tid - 256];
    if (tid < 64) {
        int i = pbase + tid;
        sVox[tid] = (i < N_PTS) ? svox[i] : -1;
    }
    // voxB rows 32-63 -> held register (1 uint4/thread, T14 issue-early).
    uint4 hv = {0u, 0u, 0u, 0u};
    int hm = 32 + (tid >> 5);          // row 32..63
    int hc = tid & 31;                 // 16B unit 0..31
    {
        int p = pbase + hm;
        if (p < N_PTS)
            hv = ((const uint4*)(voxB + (size_t)svox[p] * 256))[hc];
    }
    // voxB rows 0-31 -> sP low 16K via DMA; 16 chunks of 1KB, chunk q = wave.
    {
        int q = wave;
        int m = 2 * q + (lane >> 5);
        int u = lane & 31;
        int p = pbase + m; if (p >= N_PTS) p = N_PTS - 1;   // clamp: garbage rows dead via sVox
        gld16(voxB + (size_t)svox[p] * 256 + (size_t)(u ^ (m & 7)) * 8,
              sP + q * 1024);
    }
    // feat2 -> sF2 via DMA; chunk q = wave = 4 rows of 256B.
    {
        int q = wave;
        int m = 4 * q + (lane >> 4);
        int u = lane & 15;
        int p = pbase + m; if (p >= N_PTS) p = N_PTS - 1;
        gld16(feat2seq + (size_t)p * 128 + (size_t)(u ^ (m & 7)) * 8,
              sF2 + q * 1024);
    }
    __syncthreads();   // drains DMA (vmcnt) + sVox/sb visible

    int n = wave * 16 + l16;    // b-frag column index (per-lane)
    int nb = wave * 16 + quad * 4;   // this thread's 4 output columns (swapped C^T)

    // GEMM3': [64][128] @ [128][256]; swapped mfma(b,a)
    f32x4 acc[4];
    #pragma unroll
    for (int mt = 0; mt < 4; mt++) acc[mt] = fzero;
    #pragma unroll
    for (int kt = 0; kt < 4; kt++) {
        bf16x8 b = *(const bf16x8*)(W3bT + n * 128 + kt * 32 + quad * 8);
        #pragma unroll
        for (int mt = 0; mt < 4; mt++) {
            int m = mt * 16 + l16;
            bf16x8 a = *(const bf16x8*)(sF2 + m * 256 + ((kt * 64 + quad * 16) ^ ((m & 7) << 4)));
            acc[mt] = __builtin_amdgcn_mfma_f32_16x16x32_bf16(b, a, acc[mt], 0, 0, 0);
        }
    }
    __syncthreads();   // all sF2 reads done — its space becomes sP rows 32-63
    // write held voxB rows 32-63 into sP (dest-swizzled LDS write)
    *(uint4*)(sP + hm * 512 + ((hc * 16) ^ ((hm & 7) << 4))) = hv;
    __syncthreads();   // voxB rows 32-63 visible
    // feat4 = relu(acc + b3 + voxpart) -> sP in-place; one uint2 RMW per mt
    {
        float4 bi = *(const float4*)&sb3[nb];
        #pragma unroll
        for (int mt = 0; mt < 4; mt++) {
            int m = mt * 16 + l16;
            char* p = sP + m * 512 + ((2 * nb) ^ ((m & 7) << 4));
            uint2 vv = *(const uint2*)p;
            float v0 = fmaxf(acc[mt][0] + bi.x + bf2f((unsigned short)vv.x), 0.f);
            float v1 = fmaxf(acc[mt][1] + bi.y + bf2f((unsigned short)(vv.x >> 16)), 0.f);
            float v2 = fmaxf(acc[mt][2] + bi.z + bf2f((unsigned short)vv.y), 0.f);
            float v3 = fmaxf(acc[mt][3] + bi.w + bf2f((unsigned short)(vv.y >> 16)), 0.f);
            uint2 pk;
            pk.x = (unsigned)f2bf(v0) | ((unsigned)f2bf(v1) << 16);
            pk.y = (unsigned)f2bf(v2) | ((unsigned)f2bf(v3) << 16);
            *(uint2*)p = pk;
        }
    }
    __syncthreads();
    #pragma unroll
    for (int mt = 0; mt < 4; mt++) acc[mt] = fzero;
    // GEMM4: [64][256] @ [256][256]; swapped mfma(b,a)
    #pragma unroll 4
    for (int kt = 0; kt < 8; kt++) {
        bf16x8 b = *(const bf16x8*)(W4T + n * 256 + kt * 32 + quad * 8);
        #pragma unroll
        for (int mt = 0; mt < 4; mt++) {
            int m = mt * 16 + l16;
            bf16x8 a = *(const bf16x8*)(sP + m * 512 + ((kt * 64 + quad * 16) ^ ((m & 7) << 4)));
            acc[mt] = __builtin_amdgcn_mfma_f32_16x16x32_bf16(b, a, acc[mt], 0, 0, 0);
        }
    }
    __syncthreads();   // all feat4 reads done before feat5 overwrite
    // feat5 = relu(acc + b4) -> sP; one uint2 store per mt
    {
        float4 bi = *(const float4*)&sb4[nb];
        #pragma unroll
        for (int mt = 0; mt < 4; mt++) {
            int m = mt * 16 + l16;
            uint2 pk;
            pk.x = (unsigned)f2bf(fmaxf(acc[mt][0] + bi.x, 0.f))
                 | ((unsigned)f2bf(fmaxf(acc[mt][1] + bi.y, 0.f)) << 16);
            pk.y = (unsigned)f2bf(fmaxf(acc[mt][2] + bi.z, 0.f))
                 | ((unsigned)f2bf(fmaxf(acc[mt][3] + bi.w, 0.f)) << 16);
            *(uint2*)(sP + m * 512 + ((2 * nb) ^ ((m & 7) << 4))) = pk;
        }
    }
    __syncthreads();
    // segmented max: c = tid&255 (256 cols), four 16-row walkers per column;
    // interior segments -> plain store, boundary -> atomicMax (k1's pattern)
    {
        int c = tid & 255, r0 = (tid >> 8) * 16;
        int cur = -1; float vmax = 0.f; int segStart = r0;
        for (int r = r0; r < r0 + 16; r++) {
            int v = sVox[r];
            float f = bf2f(*(const unsigned short*)(sP + r * 512 + ((2 * c) ^ ((r & 7) << 4))));
            if (v != cur) {
                if (cur >= 0) {
                    if (segStart > r0)
                        vox2acc[(size_t)cur * 256 + c] = __float_as_uint(vmax);
                    else
                        atomicMax(vox2acc + (size_t)cur * 256 + c, __float_as_uint(vmax));
                }
                cur = v; vmax = f; segStart = r;
            } else vmax = fmaxf(vmax, f);
        }
        if (cur >= 0)
            atomicMax(vox2acc + (size_t)cur * 256 + c, __float_as_uint(vmax));
    }
}

// ---------------------------------------------------------------------------
// K3 v8 (FALLBACK, used only when workspace can't hold feat2seq):
// recomputes feat1/feat2 per tile. Unchanged from previous best.
// ---------------------------------------------------------------------------
__global__ __launch_bounds__(256, 3) void k3_heavy(
    const float* __restrict__ inp,
    const int* __restrict__ order, const int* __restrict__ svox,
    const unsigned short* __restrict__ W1T, const float* __restrict__ b1,
    const unsigned short* __restrict__ W2T, const float* __restrict__ b2,
    const unsigned short* __restrict__ voxB,     // [V][256] bf16
    const unsigned short* __restrict__ W3bT, const float* __restrict__ b3,
    const unsigned short* __restrict__ W4T, const float* __restrict__ b4,
    unsigned int* __restrict__ vox2acc)          // [V][256] fp32-as-uint (zeroed)
{
    __shared__ __align__(16) char sBuf[32 * 1024];
    __shared__ float sb1[64];
    __shared__ float sb2[128];
    __shared__ float sb3[256];
    __shared__ float sb4[256];
    __shared__ int   sVox[64];
    char* sF2 = sBuf;                 // [64][128] bf16, row 256B  (dies after GEMM3')
    char* sF1 = sBuf + 16 * 1024;     // [64][64]  bf16, row 128B  (phase 1-2)
    char* sIn = sBuf + 24 * 1024;     // [64][32]  bf16, row 64B   (phase 0-1)
    char* sP  = sBuf;                 // [64][256] bf16, row 512B  (gather onward)
    const f32x4 fzero = {0.f, 0.f, 0.f, 0.f};
    int tid = threadIdx.x;
    int pbase = blockIdx.x * 64;
    sb3[tid] = b3[tid];
    sb4[tid] = b4[tid];
    if (tid < 64)  sb1[tid] = b1[tid];
    if (tid < 128) sb2[tid] = b2[tid];
    if (tid < 64) {
        int i = pbase + tid;
        int pt = -1, v = -1;
        if (i < N_PTS) { pt = order[i]; v = svox[i]; }
        sVox[tid] = v;
        uint4 g0 = {0u, 0u, 0u, 0u};
        if (pt >= 0) {
            const float* x = inp + (size_t)pt * 6;
            g0.x = (unsigned)f2bf(x[0]) | ((unsigned)f2bf(x[1]) << 16);
            g0.y = (unsigned)f2bf(x[2]) | ((unsigned)f2bf(x[3]) << 16);
            g0.z = (unsigned)f2bf(x[4]) | ((unsigned)f2bf(x[5]) << 16);
        }
        int swz = (tid & 3) << 4;
        char* row = sIn + tid * 64;
        uint4 z = {0u, 0u, 0u, 0u};
        *(uint4*)(row + (0  ^ swz)) = g0;
        *(uint4*)(row + (16 ^ swz)) = z;
        *(uint4*)(row + (32 ^ swz)) = z;
        *(uint4*)(row + (48 ^ swz)) = z;
    }
    __syncthreads();
    int wave = tid >> 6, lane = tid & 63, quad = lane >> 4, l16 = lane & 15;

    // GEMM1: feat1 = relu([64][32]@[32][64] + b1); wave owns n-tile `wave`
    {
        f32x4 acc1[4];
        #pragma unroll
        for (int mt = 0; mt < 4; mt++) acc1[mt] = fzero;
        int n = wave * 16 + l16;
        bf16x8 b = *(const bf16x8*)(W1T + n * 32 + quad * 8);
        #pragma unroll
        for (int mt = 0; mt < 4; mt++) {
            int m = mt * 16 + l16;
            bf16x8 a = *(const bf16x8*)(sIn + m * 64 + ((quad * 16) ^ ((m & 3) << 4)));
            acc1[mt] = __builtin_amdgcn_mfma_f32_16x16x32_bf16(a, b, acc1[mt], 0, 0, 0);
        }
        float bias = sb1[n];
        #pragma unroll
        for (int mt = 0; mt < 4; mt++)
            #pragma unroll
            for (int r = 0; r < 4; r++) {
                int m = mt * 16 + quad * 4 + r;
                float v = fmaxf(acc1[mt][r] + bias, 0.f);
                *(unsigned short*)(sF1 + m * 128 + ((2 * n) ^ ((m & 7) << 4))) = f2bf(v);
            }
    }
    __syncthreads();
    // GEMM2: feat2 = relu([64][64]@[64][128] + b2); wave owns n-tiles 2w,2w+1
    {
        f32x4 acc2[2][4];
        #pragma unroll
        for (int j = 0; j < 2; j++)
            #pragma unroll
            for (int mt = 0; mt < 4; mt++) acc2[j][mt] = fzero;
        #pragma unroll
        for (int kt = 0; kt < 2; kt++) {
            bf16x8 b0 = *(const bf16x8*)(W2T + ((wave * 2 + 0) * 16 + l16) * 64 + kt * 32 + quad * 8);
            bf16x8 b1 = *(const bf16x8*)(W2T + ((wave * 2 + 1) * 16 + l16) * 64 + kt * 32 + quad * 8);
            #pragma unroll
            for (int mt = 0; mt < 4; mt++) {
                int m = mt * 16 + l16;
                bf16x8 a = *(const bf16x8*)(sF1 + m * 128 + ((kt * 64 + quad * 16) ^ ((m & 7) << 4)));
                acc2[0][mt] = __builtin_amdgcn_mfma_f32_16x16x32_bf16(a, b0, acc2[0][mt], 0, 0, 0);
                acc2[1][mt] = __builtin_amdgcn_mfma_f32_16x16x32_bf16(a, b1, acc2[1][mt], 0, 0, 0);
            }
        }
        #pragma unroll
        for (int j = 0; j < 2; j++) {
            int n = (wave * 2 + j) * 16 + l16;
            float bias = sb2[n];
            #pragma unroll
            for (int mt = 0; mt < 4; mt++)
                #pragma unroll
                for (int r = 0; r < 4; r++) {
                    int m = mt * 16 + quad * 4 + r;
                    float v = fmaxf(acc2[j][mt][r] + bias, 0.f);
                    *(unsigned short*)(sF2 + m * 256 + ((2 * n) ^ ((m & 7) << 4))) = f2bf(v);
                }
        }
    }
    __syncthreads();   // sF1/sIn dead; sF2 complete

    // GEMM3': [64][128] @ [128][256]; wave owns 4 n-tiles x 4 m-tiles
    f32x4 acc[4][4];
    #pragma unroll
    for (int j = 0; j < 4; j++)
        #pragma unroll
        for (int mt = 0; mt < 4; mt++) acc[j][mt] = fzero;
    #pragma unroll 1
    for (int kt = 0; kt < 4; kt++) {
        bf16x8 a[4];
        #pragma unroll
        for (int mt = 0; mt < 4; mt++) {
            int m = mt * 16 + l16;
            a[mt] = *(const bf16x8*)(sF2 + m * 256 + ((kt * 64 + quad * 16) ^ ((m & 7) << 4)));
        }
        #pragma unroll
        for (int j = 0; j < 4; j++) {
            int n = (wave * 4 + j) * 16 + l16;
            bf16x8 b = *(const bf16x8*)(W3bT + n * 128 + kt * 32 + quad * 8);
            #pragma unroll
            for (int mt = 0; mt < 4; mt++)
                acc[j][mt] = __builtin_amdgcn_mfma_f32_16x16x32_bf16(a[mt], b, acc[j][mt], 0, 0, 0);
        }
    }
    __syncthreads();   // sF2 reads complete — arena becomes sP
    // gather voxB rows -> sP [64][256] (sorted -> dedup, L2 hits)
    #pragma unroll
    for (int it = 0; it < 8; it++) {
        int i = tid + 256 * it;
        int m = i >> 5, c = i & 31;
        int vv = sVox[m];
        uint4 val = {0u, 0u, 0u, 0u};
        if (vv >= 0)
            val = ((const uint4*)(voxB + (size_t)vv * 256))[c];
        *(uint4*)(sP + m * 512 + ((c * 16) ^ ((m & 7) << 4))) = val;
    }
    __syncthreads();
    // feat4 = relu(acc + b3 + voxpart) -> sP in-place
    #pragma unroll
    for (int j = 0; j < 4; j++) {
        int n = (wave * 4 + j) * 16 + l16;
        float bias = sb3[n];
        #pragma unroll
        for (int mt = 0; mt < 4; mt++)
            #pragma unroll
            for (int r = 0; r < 4; r++) {
                int m = mt * 16 + quad * 4 + r;
                char* p = sP + m * 512 + ((2 * n) ^ ((m & 7) << 4));
                float vox = bf2f(*(const unsigned short*)p);
                float v = fmaxf(acc[j][mt][r] + bias + vox, 0.f);
                *(unsigned short*)p = f2bf(v);
            }
    }
    __syncthreads();
    #pragma unroll
    for (int j = 0; j < 4; j++)
        #pragma unroll
        for (int mt = 0; mt < 4; mt++) acc[j][mt] = fzero;
    // GEMM4: [64][256] @ [256][256]
    #pragma unroll 1
    for (int kt = 0; kt < 8; kt++) {
        bf16x8 a[4];
        #pragma unroll
        for (int mt = 0; mt < 4; mt++) {
            int m = mt * 16 + l16;
            a[mt] = *(const bf16x8*)(sP + m * 512 + ((kt * 64 + quad * 16) ^ ((m & 7) << 4)));
        }
        #pragma unroll
        for (int j = 0; j < 4; j++) {
            int n = (wave * 4 + j) * 16 + l16;
            bf16x8 b = *(const bf16x8*)(W4T + n * 256 + kt * 32 + quad * 8);
            #pragma unroll
            for (int mt = 0; mt < 4; mt++)
                acc[j][mt] = __builtin_amdgcn_mfma_f32_16x16x32_bf16(a[mt], b, acc[j][mt], 0, 0, 0);
        }
    }
    __syncthreads();   // all feat4 reads done before feat5 overwrite
    // feat5 = relu(acc + b4) -> sP
    #pragma unroll
    for (int j = 0; j < 4; j++) {
        int n = (wave * 4 + j) * 16 + l16;
        float bias = sb4[n];
        #pragma unroll
        for (int mt = 0; mt < 4; mt++)
            #pragma unroll
            for (int r = 0; r < 4; r++) {
                int m = mt * 16 + quad * 4 + r;
                float v = fmaxf(acc[j][mt][r] + bias, 0.f);
                *(unsigned short*)(sP + m * 512 + ((2 * n) ^ ((m & 7) << 4))) = f2bf(v);
            }
    }
    __syncthreads();
    // segmented max: c = tid (256 cols), 64 rows; interior -> plain store
    {
        int c = tid;
        int cur = -1; float vmax = 0.f; int segStart = 0;
        for (int r = 0; r < 64; r++) {
            int v = sVox[r];
            float f = bf2f(*(const unsigned short*)(sP + r * 512 + ((2 * c) ^ ((r & 7) << 4))));
            if (v != cur) {
                if (cur >= 0) {
                    if (segStart > 0)
                        vox2acc[(size_t)cur * 256 + c] = __float_as_uint(vmax);
                    else
                        atomicMax(vox2acc + (size_t)cur * 256 + c, __float_as_uint(vmax));
                }
                cur = v; vmax = f; segStart = r;
            } else vmax = fmaxf(vmax, f);
        }
        if (cur >= 0)
            atomicMax(vox2acc + (size_t)cur * 256 + c, __float_as_uint(vmax));
    }
}

// ---------------------------------------------------------------------------
// Final voxel MLP: out = relu(in @ Wv2 + bv2); safe for in == out.
// (R11 measured-best form.)
// ---------------------------------------------------------------------------
__global__ __launch_bounds__(256, 4) void kvox_final(
    const float* __restrict__ in, const unsigned short* __restrict__ WT,
    const float* __restrict__ bias, float* __restrict__ outp)
{
    __shared__ __align__(16) char sA[64 * 512];
    __shared__ float sb[256];
    const f32x4 fzero = {0.f, 0.f, 0.f, 0.f};
    int tid = threadIdx.x;
    int vb = blockIdx.x * 64;
    sb[tid] = bias[tid];
    #pragma unroll
    for (int it = 0; it < 16; it++) {
        int i = tid + 256 * it;
        int m = i >> 6, kq = i & 63;
        float4 f = ((const float4*)(in + (size_t)(vb + m) * 256))[kq];
        uint2 p;
        p.x = (unsigned)f2bf(f.x) | ((unsigned)f2bf(f.y) << 16);
        p.y = (unsigned)f2bf(f.z) | ((unsigned)f2bf(f.w) << 16);
        *(uint2*)(sA + m * 512 + ((8 * kq) ^ ((m & 7) << 4))) = p;
    }
    __syncthreads();
    int wave = tid >> 6, lane = tid & 63, quad = lane >> 4, l16 = lane & 15;
    f32x4 acc[4][4];
    #pragma unroll
    for (int j = 0; j < 4; j++)
        #pragma unroll
        for (int mt = 0; mt < 4; mt++) acc[j][mt] = fzero;
    #pragma unroll 1
    for (int kt = 0; kt < 8; kt++) {
        bf16x8 a[4];
        #pragma unroll
        for (int mt = 0; mt < 4; mt++) {
            int m = mt * 16 + l16;
            a[mt] = *(const bf16x8*)(sA + m * 512 + ((kt * 64 + quad * 16) ^ ((m & 7) << 4)));
        }
        #pragma unroll
        for (int j = 0; j < 4; j++) {
            int n = (wave * 4 + j) * 16 + l16;
            bf16x8 b = *(const bf16x8*)(WT + n * 256 + kt * 32 + quad * 8);
            #pragma unroll
            for (int mt = 0; mt < 4; mt++)
                acc[j][mt] = __builtin_amdgcn_mfma_f32_16x16x32_bf16(a[mt], b, acc[j][mt], 0, 0, 0);
        }
    }
    #pragma unroll
    for (int j = 0; j < 4; j++) {
        int n = (wave * 4 + j) * 16 + l16;
        float bi = sb[n];
        #pragma unroll
        for (int mt = 0; mt < 4; mt++)
            #pragma unroll
            for (int r = 0; r < 4; r++) {
                int m = mt * 16 + quad * 4 + r;
                outp[(size_t)(vb + m) * 256 + n] = fmaxf(acc[j][mt][r] + bi, 0.f);
            }
    }
}

extern "C" void kernel_launch(void* const* d_in, const int* in_sizes, int n_in,
                              void* d_out, int out_size, void* d_ws, size_t ws_size,
                              hipStream_t stream) {
    const float* inp  = (const float*)d_in[0];
    const int*   idx  = (const int*)d_in[1];
    const float* W1   = (const float*)d_in[2];
    const float* b1   = (const float*)d_in[3];
    const float* W2   = (const float*)d_in[4];
    const float* b2   = (const float*)d_in[5];
    const float* Wv1  = (const float*)d_in[6];
    const float* bv1  = (const float*)d_in[7];
    const float* W3   = (const float*)d_in[8];
    const float* b3   = (const float*)d_in[9];
    const float* W4   = (const float*)d_in[10];
    const float* b4   = (const float*)d_in[11];
    const float* Wv2  = (const float*)d_in[12];
    const float* bv2  = (const float*)d_in[13];

    // workspace layout — base ~38 MB; +122 MB feat2seq when it fits
    char* ws = (char*)d_ws;
    size_t off = 0;
    unsigned int*   vox1acc = (unsigned int*)(ws + off);   off += (size_t)NVOX * 128 * 4;  // 32 MB
    unsigned int*   counts  = (unsigned int*)(ws + off);   off += (size_t)NVOX * 4;
    unsigned int*   cursor  = (unsigned int*)(ws + off);   off += (size_t)NVOX * 4;
    int*            order   = (int*)(ws + off);            off += (size_t)N_PTS * 4;
    int*            svox    = (int*)(ws + off);            off += (size_t)N_PTS * 4;
    unsigned short* wsW     = (unsigned short*)(ws + off); off += (size_t)W_TOTAL * 2;

    unsigned short* feat2seq = nullptr;                    // [N][128] bf16 sorted
    if (ws_size >= off + (size_t)N_PTS * 128 * 2)
        feat2seq = (unsigned short*)(ws + off);

    const unsigned short* W1T  = wsW + WOFF_W1T;
    const unsigned short* W2T  = wsW + WOFF_W2T;
    const unsigned short* Wv1T = wsW + WOFF_WV1T;
    const unsigned short* W3aT = wsW + WOFF_W3AT;
    const unsigned short* W3bT = wsW + WOFF_W3BT;
    const unsigned short* W4T  = wsW + WOFF_W4T;
    const unsigned short* Wv2T = wsW + WOFF_WV2T;

    unsigned short* voxB = (unsigned short*)vox1acc;       // [V][256] bf16, in-place
    unsigned int* vox2acc = (unsigned int*)d_out;          // [V][256] — aliased with output

    hipMemsetAsync(vox1acc, 0, (size_t)NVOX * 128 * 4 + (size_t)NVOX * 4, stream); // +counts
    hipMemsetAsync(vox2acc, 0, (size_t)NVOX * 256 * 4, stream);

    prep_all<<<(W_TOTAL + 255) / 256, 256, 0, stream>>>(W1, W2, Wv1, W3, W4, Wv2, wsW);

    s_hist<<<(N_PTS + 255) / 256, 256, 0, stream>>>(idx, counts);
    s_scan<<<1, 1024, 0, stream>>>(counts, cursor);
    s_scatter<<<(N_PTS + 255) / 256, 256, 0, stream>>>(idx, cursor, order, svox);

    k1_points<<<K1_TILES, 512, 0, stream>>>(inp, order, svox, W1T, b1, W2T, b2,
                                            vox1acc, feat2seq);
    kvox2<<<NVOX / 64, 256, 0, stream>>>((const float*)vox1acc, Wv1T, bv1, W3aT, voxB);
    if (feat2seq)
        k3_lite<<<K3_TILES, 1024, 0, stream>>>(svox, feat2seq, voxB,
                                               W3bT, b3, W4T, b4, vox2acc);
    else
        k3_heavy<<<K3_TILES, 256, 0, stream>>>(inp, order, svox, W1T, b1, W2T, b2, voxB,
                                               W3bT, b3, W4T, b4, vox2acc);
    kvox_final<<<NVOX / 64, 256, 0, stream>>>((const float*)vox2acc, Wv2T, bv2,
                                              (float*)d_out);
}